// Round 7
// baseline (227.566 us; speedup 1.0000x reference)
//
#include <hip/hip_runtime.h>
#include <hip/hip_bf16.h>

// GCN 2-layer, slack-bucket dst-radix-sort + batched wave gathers:
//   init: zero gcursor + pre-swizzle W1 -> bf16 fragment order (wfg)
//   fused dispatch: blocks [0,pblocks) partition edges into slack bucket
//     regions (REGISTER-staged single global pass, shuffle scan ~6 barriers,
//     LDS group -> coalesced run writes); blocks [pblocks,..) do
//     h1 = bf16(bf16(x) @ bf16(W1)) via MFMA (W1 frags from wfg; x via LDS)
//   sort2 (split): TWO blocks per bucket; each hists the whole bucket,
//     stages+scatters its half (counting sort by dst&255) -> es2 + off2
//   gather1 (LDS edge staging + node-pair interleave): 16 lanes/row dwordx2,
//     nodes (j,j+8) processed together -> 8 gathers in flight; layer2 MFMA
//   gather2 (LDS edge staging + node-pair interleave): 8 lanes/row dwordx2

typedef unsigned short u16;
typedef unsigned int uint;
typedef short short8 __attribute__((ext_vector_type(8)));
typedef float floatx4 __attribute__((ext_vector_type(4)));

static __device__ __forceinline__ u16 f2bf(float f) {
    unsigned int u = __float_as_uint(f);
    return (u16)((u + 0x7fff + ((u >> 16) & 1)) >> 16);   // RNE
}

#define F4C(v, j) ((j)==0?(v).x:((j)==1?(v).y:((j)==2?(v).z:(v).w)))
#define CHUNK 2048
#define ECAP 384   // per-wave LDS edge-buffer capacity (mean 256, +8 sigma)

// ------- init: zero gcursor + W1 (128x64 f32) -> bf16 B-fragment order -----
__global__ __launch_bounds__(256) void init_kernel(
    const float* __restrict__ W1, u16* __restrict__ wfg, int* __restrict__ gcursor)
{
    const int idx = blockIdx.x * 256 + threadIdx.x;       // grid 8x256 = 2048
    if (idx < 512) gcursor[idx] = 0;
    const float4 v = ((const float4*)W1)[idx];
    const int k = idx >> 4, n4 = (idx & 15) * 4;
    const int step = k >> 5, klane = (k >> 3) & 3, j = k & 7;
    #pragma unroll
    for (int c = 0; c < 4; c++) {
        int n = n4 + c;
        wfg[(((n >> 4) * 4 + step) * 64 + klane * 16 + (n & 15)) * 8 + j] = f2bf(F4C(v, c));
    }
}

// ------- fused: partition (blocks 0..pblocks-1) + GEMM h1=x@W1 (rest) -------
// edge entry: x = src | (dst&255)<<24 ; y = w bits
union __align__(16) SharedU {
    struct {                                   // GEMM part (33.8 KB)
        u16 xs[64][136];
        u16 wf[4][4][64][8];                   // [ntile][step][lane][j]
    } g;
    struct {                                   // partition part (26.8 KB)
        int2 stage[CHUNK];                     // 16 KB
        u16  stb[CHUNK];                       // 4 KB
        int  hist[512], xscan[512], place[512], runbase[512];
        int  wsum[4];
    } p;
};

__global__ __launch_bounds__(256, 4) void g1p_kernel(
    const float* __restrict__ x, const u16* __restrict__ wfg,
    u16* __restrict__ h1, int N,
    const int* __restrict__ src, const int* __restrict__ dst,
    const float* __restrict__ w, int* __restrict__ gcursor,
    int2* __restrict__ es, int E, int cap, int pblocks)
{
    __shared__ SharedU sh;
    const int tid = threadIdx.x;

    if (blockIdx.x < pblocks) {            // ---------- partition ----------
        const int base = blockIdx.x * CHUNK;
        const int nloc = min(CHUNK, E - base);
        const int lane = tid & 63, wv = tid >> 6;

        // single global pass: edges -> registers (coalesced)
        int  rd[8]; int2 re[8];
        #pragma unroll
        for (int k = 0; k < 8; k++) {
            int i = tid + k * 256;
            if (i < nloc) {
                int d = dst[base + i];
                rd[k] = d;
                re[k] = make_int2(src[base + i] | ((d & 255) << 24),
                                  __float_as_int(w[base + i]));
            } else rd[k] = -1;
        }

        sh.p.hist[tid] = 0; sh.p.hist[tid + 256] = 0;
        __syncthreads();
        #pragma unroll
        for (int k = 0; k < 8; k++)
            if (rd[k] >= 0) atomicAdd(&sh.p.hist[rd[k] >> 8], 1);
        __syncthreads();

        // shuffle-based exclusive scan over 512 buckets (thread t owns 2t, 2t+1)
        const int h0 = sh.p.hist[2*tid], h1e = sh.p.hist[2*tid + 1];
        const int sp = h0 + h1e;
        int s = sp;
        #pragma unroll
        for (int d = 1; d < 64; d <<= 1) {
            int u = __shfl_up(s, d, 64);
            if (lane >= d) s += u;
        }
        if (lane == 63) sh.p.wsum[wv] = s;
        __syncthreads();
        int woff = 0;
        #pragma unroll
        for (int i = 0; i < 4; i++) if (i < wv) woff += sh.p.wsum[i];
        const int ex_pair = s + woff - sp;            // sum of hist[0..2t-1]
        sh.p.xscan[2*tid]     = ex_pair;
        sh.p.xscan[2*tid + 1] = ex_pair + h0;
        sh.p.place[2*tid]     = ex_pair;
        sh.p.place[2*tid + 1] = ex_pair + h0;
        __syncthreads();

        #pragma unroll
        for (int k = 0; k < 8; k++) {                 // group by bucket in LDS
            if (rd[k] >= 0) {
                int b = rd[k] >> 8;
                int pos = atomicAdd(&sh.p.place[b], 1);
                sh.p.stage[pos] = re[k];
                sh.p.stb[pos] = (u16)b;
            }
        }
        __syncthreads();

        {   // reserve runs in slack regions
            int l0 = sh.p.hist[tid], l1 = sh.p.hist[tid + 256];
            sh.p.runbase[tid]       = l0 ? atomicAdd(&gcursor[tid], l0)       : 0;
            sh.p.runbase[tid + 256] = l1 ? atomicAdd(&gcursor[tid + 256], l1) : 0;
        }
        __syncthreads();

        for (int i = tid; i < nloc; i += 256) {      // contiguous run writes
            int b = sh.p.stb[i];
            es[(size_t)b * cap + sh.p.runbase[b] + (i - sh.p.xscan[b])] = sh.p.stage[i];
        }
        return;
    }

    // ---------- GEMM ----------
    const int row0 = (blockIdx.x - pblocks) * 64;
    {   // copy pre-swizzled W1 fragments (16 KB), conflict-free
        const float4* wg4 = (const float4*)wfg;
        float4* wl4 = (float4*)&sh.g.wf[0][0][0][0];
        #pragma unroll
        for (int i = 0; i < 4; i++) wl4[tid + i*256] = wg4[tid + i*256];
    }
    {   // stage x tile -> bf16
        const float4* x4 = (const float4*)x;
        #pragma unroll
        for (int i = 0; i < 8; i++) {
            int idx = tid + i*256;
            int r = idx >> 5, kc = idx & 31;
            int gr = row0 + r;
            float4 v = make_float4(0.f,0.f,0.f,0.f);
            if (gr < N) v = x4[gr*32 + kc];
            ushort4 o;
            o.x = f2bf(v.x); o.y = f2bf(v.y); o.z = f2bf(v.z); o.w = f2bf(v.w);
            *(ushort4*)&sh.g.xs[r][kc*4] = o;
        }
    }
    __syncthreads();

    const int wave = tid >> 6, lane = tid & 63;
    const int m = lane & 15, quad = lane >> 4;
    const int rw = wave * 16;

    floatx4 acc[4] = {(floatx4)(0.f), (floatx4)(0.f), (floatx4)(0.f), (floatx4)(0.f)};
    #pragma unroll
    for (int step = 0; step < 4; step++) {
        short8 a = *(const short8*)&sh.g.xs[rw + m][step*32 + quad*8];
        #pragma unroll
        for (int nt = 0; nt < 4; nt++) {
            short8 b = *(const short8*)&sh.g.wf[nt][step][lane][0];
            acc[nt] = __builtin_amdgcn_mfma_f32_16x16x32_bf16(a, b, acc[nt], 0, 0, 0);
        }
    }
    #pragma unroll
    for (int nt = 0; nt < 4; nt++) {
        #pragma unroll
        for (int r = 0; r < 4; r++) {
            int gr = row0 + rw + quad*4 + r;
            if (gr < N) h1[(size_t)gr*64 + nt*16 + m] = f2bf(acc[nt][r]);
        }
    }
}

// ------- sort2 (split): 2 blocks/bucket; each block hists the full bucket,
//   stages + scatters only its half. Counting sort by dst&255 -> es2, off2 --
#define SCAP2 2304
__global__ __launch_bounds__(512, 4) void sort2_kernel(
    const int2* __restrict__ es, const int* __restrict__ gcursor,
    int2* __restrict__ es2, int2* __restrict__ off2, int N, int cap, int nb)
{
    __shared__ int2 stage[SCAP2];                 // 18.4 KB (half-bucket)
    __shared__ int hA[256], hB[256], sc[256], cur[256];
    const int t = threadIdx.x;
    const int b = blockIdx.x >> 1, h = blockIdx.x & 1;
    const int e0 = b * cap;
    const int len = gcursor[b];
    const int len1 = (len + 1) >> 1;              // half0=[0,len1) half1=[len1,len)

    if (t < 256) { hA[t] = 0; hB[t] = 0; }
    __syncthreads();
    for (int i = t; i < len; i += 512) {          // full hist; stage own half
        int2 e = es[e0 + i];
        int k = ((unsigned)e.x) >> 24;
        if (i < len1) { atomicAdd(&hA[k], 1); if (h == 0) stage[i] = e; }
        else          { atomicAdd(&hB[k], 1); if (h == 1) stage[i - len1] = e; }
    }
    __syncthreads();

    int v = 0;
    if (t < 256) { v = hA[t] + hB[t]; sc[t] = v; }
    __syncthreads();
    for (int o = 1; o < 256; o <<= 1) {
        int add = 0;
        if (t < 256 && t >= o) add = sc[t - o];
        __syncthreads();
        if (t < 256) sc[t] += add;
        __syncthreads();
    }
    if (t < 256) {
        int ex = sc[t] - v;                       // exclusive within bucket
        cur[t] = ex + (h ? hA[t] : 0);            // half1 starts after half0's k-run
        if (h == 0) {
            int g = b * 256 + t;
            if (g < N) off2[g] = make_int2(e0 + ex, e0 + ex + v);
        }
    }
    __syncthreads();

    const int myn = h ? (len - len1) : len1;
    for (int i = t; i < myn; i += 512) {
        int2 e = stage[i];
        int pos = e0 + atomicAdd(&cur[((unsigned)e.x) >> 24], 1);
        es2[pos] = e;                             // scatter within 36 KB window
    }
}

// ------- gather1: 64 nodes/block, wave stages its contiguous edge range in
//   LDS; node-pair (j, j+8) interleave -> 8 edge reads + 8 h1 gathers in
//   flight per iter; 16 lanes/row dwordx2; layer2 (relu(+b1) @ W2) via MFMA --
__global__ __launch_bounds__(256, 4) void gather1_kernel(
    const u16* __restrict__ h1, const int2* __restrict__ es,
    const int2* __restrict__ off2, const float* __restrict__ b1,
    const float* __restrict__ W2, u16* __restrict__ h2, int N)
{
    __shared__ __align__(16) u16 ts[64][72];          // t rows, bf16 (144B rows)
    __shared__ __align__(16) u16 wf2[2][2][64][8];    // [ntile][step][lane][j]
    __shared__ float b1s[64];
    __shared__ int2 eb[4][ECAP];                      // per-wave edge buffer
    const int tid = threadIdx.x;

    {   // stage W2 (64x32 f32 = 512 float4) -> bf16 B-fragments, + b1
        const float4* s4 = (const float4*)W2;
        #pragma unroll
        for (int i = 0; i < 2; i++) {
            int idx = tid + i*256;
            float4 v = s4[idx];
            int k = idx >> 3, n4 = (idx & 7) * 4;
            int step = k >> 5, quad = (k >> 3) & 3, j = k & 7;
            #pragma unroll
            for (int c = 0; c < 4; c++) {
                int n = n4 + c;
                wf2[n >> 4][step][quad*16 + (n & 15)][j] = f2bf(F4C(v, c));
            }
        }
        if (tid < 16) ((float4*)b1s)[tid] = ((const float4*)b1)[tid];
    }
    __syncthreads();

    const int wave = tid >> 6, lane = tid & 63;
    const int h = lane >> 4, fl = lane & 15;          // slot 0..3, ch-group 0..15
    const int node0 = blockIdx.x * 64 + wave * 16;
    const uint2* h1v = (const uint2*)h1;   // h1 row = 16 uint2 (64 bf16, 128B)
    uint* tsu = (uint*)&ts[0][0];          // rows of 36 uints

    // prefetch segments (lanes 0..15; clamp keeps OOB waves harmless)
    const int2 sg = off2[min(node0 + fl, N - 1)];
    const int beg = __builtin_amdgcn_readfirstlane(sg.x);
    const int end = __builtin_amdgcn_readlane(sg.y, 15);
    const int len = end - beg;

    if (len <= ECAP) {
        // ---- stage wave's whole edge range into LDS (coalesced) ----
        for (int k = lane; k < len; k += 64) eb[wave][k] = es[beg + k];
        // intra-wave LDS write->read ordering: compiler lgkmcnt

        #pragma unroll 1
        for (int j = 0; j < 8; j++) {                 // node pair (j, j+8)
            const int pbegA = __builtin_amdgcn_readlane(sg.x, j) - beg;
            const int pendA = __builtin_amdgcn_readlane(sg.y, j) - beg;
            const int pbegB = __builtin_amdgcn_readlane(sg.x, j + 8) - beg;
            const int pendB = __builtin_amdgcn_readlane(sg.y, j + 8) - beg;
            const int clA = max(pendA - 1, 0), clB = max(pendB - 1, 0);
            float a0 = 0.f, a1 = 0.f, a2 = 0.f, a3 = 0.f;
            float c0 = 0.f, c1 = 0.f, c2 = 0.f, c3 = 0.f;
            int pA = pbegA, pB = pbegB;
            #pragma unroll 1
            while (pA < pendA || pB < pendB) {        // 16+16 edges, 8 gathers
                const int iA0 = pA + h,     iA1 = pA + 4 + h;
                const int iA2 = pA + 8 + h, iA3 = pA + 12 + h;
                const int iB0 = pB + h,     iB1 = pB + 4 + h;
                const int iB2 = pB + 8 + h, iB3 = pB + 12 + h;
                int2 eA0 = eb[wave][min(iA0, clA)];
                int2 eA1 = eb[wave][min(iA1, clA)];
                int2 eA2 = eb[wave][min(iA2, clA)];
                int2 eA3 = eb[wave][min(iA3, clA)];
                int2 eB0 = eb[wave][min(iB0, clB)];
                int2 eB1 = eb[wave][min(iB1, clB)];
                int2 eB2 = eb[wave][min(iB2, clB)];
                int2 eB3 = eb[wave][min(iB3, clB)];
                uint2 vA0 = h1v[(size_t)(eA0.x & 0xFFFFFF) * 16 + fl];
                uint2 vA1 = h1v[(size_t)(eA1.x & 0xFFFFFF) * 16 + fl];
                uint2 vA2 = h1v[(size_t)(eA2.x & 0xFFFFFF) * 16 + fl];
                uint2 vA3 = h1v[(size_t)(eA3.x & 0xFFFFFF) * 16 + fl];
                uint2 vB0 = h1v[(size_t)(eB0.x & 0xFFFFFF) * 16 + fl];
                uint2 vB1 = h1v[(size_t)(eB1.x & 0xFFFFFF) * 16 + fl];
                uint2 vB2 = h1v[(size_t)(eB2.x & 0xFFFFFF) * 16 + fl];
                uint2 vB3 = h1v[(size_t)(eB3.x & 0xFFFFFF) * 16 + fl];
                float wA0 = (iA0 < pendA) ? __int_as_float(eA0.y) : 0.f;
                float wA1 = (iA1 < pendA) ? __int_as_float(eA1.y) : 0.f;
                float wA2 = (iA2 < pendA) ? __int_as_float(eA2.y) : 0.f;
                float wA3 = (iA3 < pendA) ? __int_as_float(eA3.y) : 0.f;
                float wB0 = (iB0 < pendB) ? __int_as_float(eB0.y) : 0.f;
                float wB1 = (iB1 < pendB) ? __int_as_float(eB1.y) : 0.f;
                float wB2 = (iB2 < pendB) ? __int_as_float(eB2.y) : 0.f;
                float wB3 = (iB3 < pendB) ? __int_as_float(eB3.y) : 0.f;
                a0 += __uint_as_float(vA0.x << 16) * wA0 + __uint_as_float(vA1.x << 16) * wA1
                    + __uint_as_float(vA2.x << 16) * wA2 + __uint_as_float(vA3.x << 16) * wA3;
                a1 += __uint_as_float(vA0.x & 0xFFFF0000u) * wA0 + __uint_as_float(vA1.x & 0xFFFF0000u) * wA1
                    + __uint_as_float(vA2.x & 0xFFFF0000u) * wA2 + __uint_as_float(vA3.x & 0xFFFF0000u) * wA3;
                a2 += __uint_as_float(vA0.y << 16) * wA0 + __uint_as_float(vA1.y << 16) * wA1
                    + __uint_as_float(vA2.y << 16) * wA2 + __uint_as_float(vA3.y << 16) * wA3;
                a3 += __uint_as_float(vA0.y & 0xFFFF0000u) * wA0 + __uint_as_float(vA1.y & 0xFFFF0000u) * wA1
                    + __uint_as_float(vA2.y & 0xFFFF0000u) * wA2 + __uint_as_float(vA3.y & 0xFFFF0000u) * wA3;
                c0 += __uint_as_float(vB0.x << 16) * wB0 + __uint_as_float(vB1.x << 16) * wB1
                    + __uint_as_float(vB2.x << 16) * wB2 + __uint_as_float(vB3.x << 16) * wB3;
                c1 += __uint_as_float(vB0.x & 0xFFFF0000u) * wB0 + __uint_as_float(vB1.x & 0xFFFF0000u) * wB1
                    + __uint_as_float(vB2.x & 0xFFFF0000u) * wB2 + __uint_as_float(vB3.x & 0xFFFF0000u) * wB3;
                c2 += __uint_as_float(vB0.y << 16) * wB0 + __uint_as_float(vB1.y << 16) * wB1
                    + __uint_as_float(vB2.y << 16) * wB2 + __uint_as_float(vB3.y << 16) * wB3;
                c3 += __uint_as_float(vB0.y & 0xFFFF0000u) * wB0 + __uint_as_float(vB1.y & 0xFFFF0000u) * wB1
                    + __uint_as_float(vB2.y & 0xFFFF0000u) * wB2 + __uint_as_float(vB3.y & 0xFFFF0000u) * wB3;
                pA += 16; pB += 16;
            }
            a0 += __shfl_xor(a0, 16, 64); a1 += __shfl_xor(a1, 16, 64);
            a2 += __shfl_xor(a2, 16, 64); a3 += __shfl_xor(a3, 16, 64);
            a0 += __shfl_xor(a0, 32, 64); a1 += __shfl_xor(a1, 32, 64);
            a2 += __shfl_xor(a2, 32, 64); a3 += __shfl_xor(a3, 32, 64);
            c0 += __shfl_xor(c0, 16, 64); c1 += __shfl_xor(c1, 16, 64);
            c2 += __shfl_xor(c2, 16, 64); c3 += __shfl_xor(c3, 16, 64);
            c0 += __shfl_xor(c0, 32, 64); c1 += __shfl_xor(c1, 32, 64);
            c2 += __shfl_xor(c2, 32, 64); c3 += __shfl_xor(c3, 32, 64);
            if (h == 0) {
                uint t0 = (uint)f2bf(fmaxf(a0 + b1s[4*fl],     0.f))
                        | ((uint)f2bf(fmaxf(a1 + b1s[4*fl + 1], 0.f)) << 16);
                uint t1 = (uint)f2bf(fmaxf(a2 + b1s[4*fl + 2], 0.f))
                        | ((uint)f2bf(fmaxf(a3 + b1s[4*fl + 3], 0.f)) << 16);
                *(uint2*)&tsu[(wave*16 + j) * 36 + 2*fl] = make_uint2(t0, t1);
                uint t2 = (uint)f2bf(fmaxf(c0 + b1s[4*fl],     0.f))
                        | ((uint)f2bf(fmaxf(c1 + b1s[4*fl + 1], 0.f)) << 16);
                uint t3 = (uint)f2bf(fmaxf(c2 + b1s[4*fl + 2], 0.f))
                        | ((uint)f2bf(fmaxf(c3 + b1s[4*fl + 3], 0.f)) << 16);
                *(uint2*)&tsu[(wave*16 + j + 8) * 36 + 2*fl] = make_uint2(t2, t3);
            }
        }
    } else {
        // ---- overflow fallback: direct global edge reads (never in practice)
        #pragma unroll 1
        for (int i = 0; i < 16; i++) {
            const int pbeg = __builtin_amdgcn_readlane(sg.x, i);
            const int pend = __builtin_amdgcn_readlane(sg.y, i);
            const int cl = max(pend - 1, 0);
            float a0 = 0.f, a1 = 0.f, a2 = 0.f, a3 = 0.f;
            #pragma unroll 1
            for (int p = pbeg; p < pend; p += 16) {
                const int i0 = p + h, i1 = p + 4 + h, i2 = p + 8 + h, i3 = p + 12 + h;
                int2 e0 = es[min(i0, cl)];
                int2 e1 = es[min(i1, cl)];
                int2 e2 = es[min(i2, cl)];
                int2 e3 = es[min(i3, cl)];
                uint2 v0 = h1v[(size_t)(e0.x & 0xFFFFFF) * 16 + fl];
                uint2 v1 = h1v[(size_t)(e1.x & 0xFFFFFF) * 16 + fl];
                uint2 v2 = h1v[(size_t)(e2.x & 0xFFFFFF) * 16 + fl];
                uint2 v3 = h1v[(size_t)(e3.x & 0xFFFFFF) * 16 + fl];
                float w0 = (i0 < pend) ? __int_as_float(e0.y) : 0.f;
                float w1 = (i1 < pend) ? __int_as_float(e1.y) : 0.f;
                float w2 = (i2 < pend) ? __int_as_float(e2.y) : 0.f;
                float w3 = (i3 < pend) ? __int_as_float(e3.y) : 0.f;
                a0 += __uint_as_float(v0.x << 16) * w0 + __uint_as_float(v1.x << 16) * w1
                    + __uint_as_float(v2.x << 16) * w2 + __uint_as_float(v3.x << 16) * w3;
                a1 += __uint_as_float(v0.x & 0xFFFF0000u) * w0 + __uint_as_float(v1.x & 0xFFFF0000u) * w1
                    + __uint_as_float(v2.x & 0xFFFF0000u) * w2 + __uint_as_float(v3.x & 0xFFFF0000u) * w3;
                a2 += __uint_as_float(v0.y << 16) * w0 + __uint_as_float(v1.y << 16) * w1
                    + __uint_as_float(v2.y << 16) * w2 + __uint_as_float(v3.y << 16) * w3;
                a3 += __uint_as_float(v0.y & 0xFFFF0000u) * w0 + __uint_as_float(v1.y & 0xFFFF0000u) * w1
                    + __uint_as_float(v2.y & 0xFFFF0000u) * w2 + __uint_as_float(v3.y & 0xFFFF0000u) * w3;
            }
            a0 += __shfl_xor(a0, 16, 64); a1 += __shfl_xor(a1, 16, 64);
            a2 += __shfl_xor(a2, 16, 64); a3 += __shfl_xor(a3, 16, 64);
            a0 += __shfl_xor(a0, 32, 64); a1 += __shfl_xor(a1, 32, 64);
            a2 += __shfl_xor(a2, 32, 64); a3 += __shfl_xor(a3, 32, 64);
            if (h == 0) {
                uint t0 = (uint)f2bf(fmaxf(a0 + b1s[4*fl],     0.f))
                        | ((uint)f2bf(fmaxf(a1 + b1s[4*fl + 1], 0.f)) << 16);
                uint t1 = (uint)f2bf(fmaxf(a2 + b1s[4*fl + 2], 0.f))
                        | ((uint)f2bf(fmaxf(a3 + b1s[4*fl + 3], 0.f)) << 16);
                *(uint2*)&tsu[(wave*16 + i) * 36 + 2*fl] = make_uint2(t0, t1);
            }
        }
    }

    // layer2 MFMA on this wave's own 16 rows (intra-wave LDS dep, in-order)
    const int m = lane & 15, quad = lane >> 4;
    floatx4 acc[2] = {(floatx4)(0.f), (floatx4)(0.f)};
    #pragma unroll
    for (int step = 0; step < 2; step++) {
        short8 a = *(const short8*)&ts[wave*16 + m][step*32 + quad*8];
        #pragma unroll
        for (int nt = 0; nt < 2; nt++) {
            short8 b = *(const short8*)&wf2[nt][step][lane][0];
            acc[nt] = __builtin_amdgcn_mfma_f32_16x16x32_bf16(a, b, acc[nt], 0, 0, 0);
        }
    }
    #pragma unroll
    for (int nt = 0; nt < 2; nt++) {
        #pragma unroll
        for (int r = 0; r < 4; r++) {
            int g = node0 + quad*4 + r;
            if (g < N) h2[(size_t)g*32 + nt*16 + m] = f2bf(acc[nt][r]);
        }
    }
}

// ------- gather2: 16 nodes/wave, LDS edge staging + node-pair interleave,
//   8 lanes/row dwordx2, 2+2 loads per iter --------------------------------
__global__ __launch_bounds__(256, 4) void gather2_kernel(
    const u16* __restrict__ h2, const int2* __restrict__ es,
    const int2* __restrict__ off2, const float* __restrict__ b2,
    float* __restrict__ out, int N)
{
    __shared__ int2 eb[4][ECAP];
    const int tid = threadIdx.x;
    const int wave = tid >> 6, lane = tid & 63;
    const int g = lane >> 3, fl = lane & 7;           // slot 0..7, ch-group 0..7
    const int node0 = blockIdx.x * 64 + wave * 16;
    const uint2* h2v = (const uint2*)h2;   // h2 row = 8 uint2 (32 bf16, 64B)

    const int2 sg = off2[min(node0 + (lane & 15), N - 1)];
    const int beg = __builtin_amdgcn_readfirstlane(sg.x);
    const int end = __builtin_amdgcn_readlane(sg.y, 15);
    const int len = end - beg;
    const float4 bb = ((const float4*)b2)[fl];

    if (len <= ECAP) {
        for (int k = lane; k < len; k += 64) eb[wave][k] = es[beg + k];

        #pragma unroll 1
        for (int j = 0; j < 8; j++) {                 // node pair (j, j+8)
            const int pbegA = __builtin_amdgcn_readlane(sg.x, j) - beg;
            const int pendA = __builtin_amdgcn_readlane(sg.y, j) - beg;
            const int pbegB = __builtin_amdgcn_readlane(sg.x, j + 8) - beg;
            const int pendB = __builtin_amdgcn_readlane(sg.y, j + 8) - beg;
            const int clA = max(pendA - 1, 0), clB = max(pendB - 1, 0);
            float a0 = 0.f, a1 = 0.f, a2 = 0.f, a3 = 0.f;
            float c0 = 0.f, c1 = 0.f, c2 = 0.f, c3 = 0.f;
            int pA = pbegA, pB = pbegB;
            #pragma unroll 1
            while (pA < pendA || pB < pendB) {        // 16+16 edges, 4 gathers
                const int iA0 = pA + g, iA1 = pA + 8 + g;
                const int iB0 = pB + g, iB1 = pB + 8 + g;
                int2 eA0 = eb[wave][min(iA0, clA)];
                int2 eA1 = eb[wave][min(iA1, clA)];
                int2 eB0 = eb[wave][min(iB0, clB)];
                int2 eB1 = eb[wave][min(iB1, clB)];
                uint2 vA0 = h2v[(size_t)(eA0.x & 0xFFFFFF) * 8 + fl];
                uint2 vA1 = h2v[(size_t)(eA1.x & 0xFFFFFF) * 8 + fl];
                uint2 vB0 = h2v[(size_t)(eB0.x & 0xFFFFFF) * 8 + fl];
                uint2 vB1 = h2v[(size_t)(eB1.x & 0xFFFFFF) * 8 + fl];
                float wA0 = (iA0 < pendA) ? __int_as_float(eA0.y) : 0.f;
                float wA1 = (iA1 < pendA) ? __int_as_float(eA1.y) : 0.f;
                float wB0 = (iB0 < pendB) ? __int_as_float(eB0.y) : 0.f;
                float wB1 = (iB1 < pendB) ? __int_as_float(eB1.y) : 0.f;
                a0 += __uint_as_float(vA0.x << 16) * wA0 + __uint_as_float(vA1.x << 16) * wA1;
                a1 += __uint_as_float(vA0.x & 0xFFFF0000u) * wA0 + __uint_as_float(vA1.x & 0xFFFF0000u) * wA1;
                a2 += __uint_as_float(vA0.y << 16) * wA0 + __uint_as_float(vA1.y << 16) * wA1;
                a3 += __uint_as_float(vA0.y & 0xFFFF0000u) * wA0 + __uint_as_float(vA1.y & 0xFFFF0000u) * wA1;
                c0 += __uint_as_float(vB0.x << 16) * wB0 + __uint_as_float(vB1.x << 16) * wB1;
                c1 += __uint_as_float(vB0.x & 0xFFFF0000u) * wB0 + __uint_as_float(vB1.x & 0xFFFF0000u) * wB1;
                c2 += __uint_as_float(vB0.y << 16) * wB0 + __uint_as_float(vB1.y << 16) * wB1;
                c3 += __uint_as_float(vB0.y & 0xFFFF0000u) * wB0 + __uint_as_float(vB1.y & 0xFFFF0000u) * wB1;
                pA += 16; pB += 16;
            }
            a0 += __shfl_xor(a0, 8, 64);  a1 += __shfl_xor(a1, 8, 64);
            a2 += __shfl_xor(a2, 8, 64);  a3 += __shfl_xor(a3, 8, 64);
            a0 += __shfl_xor(a0, 16, 64); a1 += __shfl_xor(a1, 16, 64);
            a2 += __shfl_xor(a2, 16, 64); a3 += __shfl_xor(a3, 16, 64);
            a0 += __shfl_xor(a0, 32, 64); a1 += __shfl_xor(a1, 32, 64);
            a2 += __shfl_xor(a2, 32, 64); a3 += __shfl_xor(a3, 32, 64);
            c0 += __shfl_xor(c0, 8, 64);  c1 += __shfl_xor(c1, 8, 64);
            c2 += __shfl_xor(c2, 8, 64);  c3 += __shfl_xor(c3, 8, 64);
            c0 += __shfl_xor(c0, 16, 64); c1 += __shfl_xor(c1, 16, 64);
            c2 += __shfl_xor(c2, 16, 64); c3 += __shfl_xor(c3, 16, 64);
            c0 += __shfl_xor(c0, 32, 64); c1 += __shfl_xor(c1, 32, 64);
            c2 += __shfl_xor(c2, 32, 64); c3 += __shfl_xor(c3, 32, 64);
            const int dA = node0 + j, dB = node0 + j + 8;
            if (g == 0 && dA < N)
                *(float4*)&out[(size_t)dA * 32 + 4 * fl] =
                    make_float4(a0 + bb.x, a1 + bb.y, a2 + bb.z, a3 + bb.w);
            if (g == 0 && dB < N)
                *(float4*)&out[(size_t)dB * 32 + 4 * fl] =
                    make_float4(c0 + bb.x, c1 + bb.y, c2 + bb.z, c3 + bb.w);
        }
    } else {
        #pragma unroll 1
        for (int i = 0; i < 16; i++) {
            const int pbeg = __builtin_amdgcn_readlane(sg.x, i);
            const int pend = __builtin_amdgcn_readlane(sg.y, i);
            const int cl = max(pend - 1, 0);
            float a0 = 0.f, a1 = 0.f, a2 = 0.f, a3 = 0.f;
            #pragma unroll 1
            for (int p = pbeg; p < pend; p += 32) {
                const int i0 = p + g, i1 = p + 8 + g, i2 = p + 16 + g, i3 = p + 24 + g;
                int2 e0 = es[min(i0, cl)];
                int2 e1 = es[min(i1, cl)];
                int2 e2 = es[min(i2, cl)];
                int2 e3 = es[min(i3, cl)];
                uint2 v0 = h2v[(size_t)(e0.x & 0xFFFFFF) * 8 + fl];
                uint2 v1 = h2v[(size_t)(e1.x & 0xFFFFFF) * 8 + fl];
                uint2 v2 = h2v[(size_t)(e2.x & 0xFFFFFF) * 8 + fl];
                uint2 v3 = h2v[(size_t)(e3.x & 0xFFFFFF) * 8 + fl];
                float w0 = (i0 < pend) ? __int_as_float(e0.y) : 0.f;
                float w1 = (i1 < pend) ? __int_as_float(e1.y) : 0.f;
                float w2 = (i2 < pend) ? __int_as_float(e2.y) : 0.f;
                float w3 = (i3 < pend) ? __int_as_float(e3.y) : 0.f;
                a0 += __uint_as_float(v0.x << 16) * w0 + __uint_as_float(v1.x << 16) * w1
                    + __uint_as_float(v2.x << 16) * w2 + __uint_as_float(v3.x << 16) * w3;
                a1 += __uint_as_float(v0.x & 0xFFFF0000u) * w0 + __uint_as_float(v1.x & 0xFFFF0000u) * w1
                    + __uint_as_float(v2.x & 0xFFFF0000u) * w2 + __uint_as_float(v3.x & 0xFFFF0000u) * w3;
                a2 += __uint_as_float(v0.y << 16) * w0 + __uint_as_float(v1.y << 16) * w1
                    + __uint_as_float(v2.y << 16) * w2 + __uint_as_float(v3.y << 16) * w3;
                a3 += __uint_as_float(v0.y & 0xFFFF0000u) * w0 + __uint_as_float(v1.y & 0xFFFF0000u) * w1
                    + __uint_as_float(v2.y & 0xFFFF0000u) * w2 + __uint_as_float(v3.y & 0xFFFF0000u) * w3;
            }
            a0 += __shfl_xor(a0, 8, 64);  a1 += __shfl_xor(a1, 8, 64);
            a2 += __shfl_xor(a2, 8, 64);  a3 += __shfl_xor(a3, 8, 64);
            a0 += __shfl_xor(a0, 16, 64); a1 += __shfl_xor(a1, 16, 64);
            a2 += __shfl_xor(a2, 16, 64); a3 += __shfl_xor(a3, 16, 64);
            a0 += __shfl_xor(a0, 32, 64); a1 += __shfl_xor(a1, 32, 64);
            a2 += __shfl_xor(a2, 32, 64); a3 += __shfl_xor(a3, 32, 64);
            const int d = node0 + i;
            if (g == 0 && d < N)
                *(float4*)&out[(size_t)d * 32 + 4 * fl] =
                    make_float4(a0 + bb.x, a1 + bb.y, a2 + bb.z, a3 + bb.w);
        }
    }
}

extern "C" void kernel_launch(void* const* d_in, const int* in_sizes, int n_in,
                              void* d_out, int out_size, void* d_ws, size_t ws_size,
                              hipStream_t stream)
{
    const float* x   = (const float*)d_in[0];
    const int*  esrc = (const int*)d_in[1];
    const int*  edst = (const int*)d_in[2];
    const float* ew  = (const float*)d_in[3];
    const float* W1  = (const float*)d_in[4];
    const float* b1  = (const float*)d_in[5];
    const float* W2  = (const float*)d_in[6];
    const float* b2  = (const float*)d_in[7];
    float* out = (float*)d_out;

    const int N = in_sizes[0] / 128;   // 100000
    const int E = in_sizes[1];         // 1600000
    const int nb = (N + 255) >> 8;     // 391 buckets

    // slack bucket capacity: mean + ~8 sigma, 16-aligned
    const int mean = (E + nb - 1) / nb;
    int s = 1; while (s * s < mean) s++;                  // ceil sqrt
    const int cap = (mean + 8 * s + 15) & ~15;            // ~4608

    char* base = (char*)d_ws;
    size_t o = 0;
    auto alloc = [&](size_t bytes) { char* p = base + o; o = (o + bytes + 255) & ~(size_t)255; return p; };
    u16*  h1      = (u16*) alloc((size_t)N * 64 * 2);
    u16*  h2      = (u16*) alloc((size_t)N * 32 * 2);
    int2* es      = (int2*)alloc((size_t)nb * cap * 8);
    int2* es2     = (int2*)alloc((size_t)nb * cap * 8);
    int2* off2    = (int2*)alloc((size_t)N * 8);
    int*  gcursor = (int*) alloc(512 * 4);
    u16*  wfg     = (u16*) alloc(8192 * 2);               // W1 frags, 16 KB

    const int pblocks = (E + CHUNK - 1) / CHUNK;   // 782 partition blocks
    const int gblocks = (N + 63) / 64;             // 1563 gemm blocks

    init_kernel<<<8, 256, 0, stream>>>(W1, wfg, gcursor);
    g1p_kernel<<<pblocks + gblocks, 256, 0, stream>>>(
        x, wfg, h1, N, esrc, edst, ew, gcursor, es, E, cap, pblocks);
    sort2_kernel<<<2 * nb, 512, 0, stream>>>(es, gcursor, es2, off2, N, cap, nb);
    gather1_kernel<<<(N + 63) / 64, 256, 0, stream>>>(h1, es2, off2, b1, W2, h2, N);
    gather2_kernel<<<(N + 63) / 64, 256, 0, stream>>>(h2, es2, off2, b2, out, N);
}

// Round 8
// 219.049 us; speedup vs baseline: 1.0389x; 1.0389x over previous
//
#include <hip/hip_runtime.h>
#include <hip/hip_bf16.h>

// GCN 2-layer, slack-bucket dst-radix-sort + batched wave gathers:
//   init: zero gcursor + pre-swizzle W1 -> bf16 fragment order (wfg)
//   fused dispatch: blocks [0,pblocks) partition edges into slack bucket
//     regions (hist -> scan -> LDS group -> coalesced run writes);
//     blocks [pblocks,..) do h1 = bf16(bf16(x) @ bf16(W1)) via MFMA
//   sg1 (FUSED sort2+gather1): one block per bucket (512 thr). Phase 1:
//     bucket edges -> regs, 256-key hist+scan, scatter SORTED into LDS,
//     coalesced es2/off2 writeback (for gather2). Phase 2: 8 waves x 32
//     nodes gather h1 from LDS-sorted edges (node-pair interleave,
//     16 lanes/row dwordx2); layer2 (relu(+b1) @ W2) via MFMA -> h2
//   gather2 (LDS edge staging + node-pair interleave): 8 lanes/row dwordx2

typedef unsigned short u16;
typedef unsigned int uint;
typedef short short8 __attribute__((ext_vector_type(8)));
typedef float floatx4 __attribute__((ext_vector_type(4)));

static __device__ __forceinline__ u16 f2bf(float f) {
    unsigned int u = __float_as_uint(f);
    return (u16)((u + 0x7fff + ((u >> 16) & 1)) >> 16);   // RNE
}

#define F4C(v, j) ((j)==0?(v).x:((j)==1?(v).y:((j)==2?(v).z:(v).w)))
#define CHUNK 2048
#define CAPC 4608  // bucket capacity (mean 4096 + 8 sigma, 16-aligned) = host cap
#define ECAP 384   // gather2 per-wave LDS edge-buffer capacity

// ------- init: zero gcursor + W1 (128x64 f32) -> bf16 B-fragment order -----
__global__ __launch_bounds__(256) void init_kernel(
    const float* __restrict__ W1, u16* __restrict__ wfg, int* __restrict__ gcursor)
{
    const int idx = blockIdx.x * 256 + threadIdx.x;       // grid 8x256 = 2048
    if (idx < 512) gcursor[idx] = 0;
    const float4 v = ((const float4*)W1)[idx];
    const int k = idx >> 4, n4 = (idx & 15) * 4;
    const int step = k >> 5, klane = (k >> 3) & 3, j = k & 7;
    #pragma unroll
    for (int c = 0; c < 4; c++) {
        int n = n4 + c;
        wfg[(((n >> 4) * 4 + step) * 64 + klane * 16 + (n & 15)) * 8 + j] = f2bf(F4C(v, c));
    }
}

// ------- fused: partition (blocks 0..pblocks-1) + GEMM h1=x@W1 (rest) -------
// edge entry: x = src | (dst&255)<<24 ; y = w bits
union __align__(16) SharedU {
    struct {                                   // GEMM part (33.8 KB)
        u16 xs[64][136];
        u16 wf[4][4][64][8];                   // [ntile][step][lane][j]
    } g;
    struct {                                   // partition part (30.7 KB)
        int2 stage[CHUNK];                     // 16 KB
        u16  stb[CHUNK];                       // 4 KB
        int  hist[512], sc[512], xscan[512], place[512], runbase[512];
    } p;
};

__global__ __launch_bounds__(256, 4) void g1p_kernel(
    const float* __restrict__ x, const u16* __restrict__ wfg,
    u16* __restrict__ h1, int N,
    const int* __restrict__ src, const int* __restrict__ dst,
    const float* __restrict__ w, int* __restrict__ gcursor,
    int2* __restrict__ es, int E, int cap, int pblocks)
{
    __shared__ SharedU sh;
    const int tid = threadIdx.x;

    if (blockIdx.x < pblocks) {            // ---------- partition ----------
        const int base = blockIdx.x * CHUNK;
        const int nloc = min(CHUNK, E - base);

        sh.p.hist[tid] = 0; sh.p.hist[tid + 256] = 0;
        __syncthreads();
        for (int i = tid; i < nloc; i += 256)
            atomicAdd(&sh.p.hist[dst[base + i] >> 8], 1);
        __syncthreads();

        sh.p.sc[tid] = sh.p.hist[tid];
        sh.p.sc[tid + 256] = sh.p.hist[tid + 256];
        __syncthreads();
        for (int o = 1; o < 512; o <<= 1) {          // inclusive scan, 512 wide
            int v0 = (tid >= o) ? sh.p.sc[tid - o] : 0;
            int v1 = (tid + 256 >= o) ? sh.p.sc[tid + 256 - o] : 0;
            __syncthreads();
            sh.p.sc[tid] += v0;
            sh.p.sc[tid + 256] += v1;
            __syncthreads();
        }
        sh.p.xscan[tid] = sh.p.sc[tid] - sh.p.hist[tid];
        sh.p.xscan[tid + 256] = sh.p.sc[tid + 256] - sh.p.hist[tid + 256];
        sh.p.place[tid] = sh.p.xscan[tid];
        sh.p.place[tid + 256] = sh.p.xscan[tid + 256];
        __syncthreads();

        for (int i = tid; i < nloc; i += 256) {      // group by bucket in LDS
            int d = dst[base + i];
            int b = d >> 8;
            int pos = atomicAdd(&sh.p.place[b], 1);
            sh.p.stage[pos] = make_int2(src[base + i] | ((d & 255) << 24),
                                        __float_as_int(w[base + i]));
            sh.p.stb[pos] = (u16)b;
        }
        __syncthreads();

        {   // reserve runs in slack regions
            int l0 = sh.p.hist[tid], l1 = sh.p.hist[tid + 256];
            sh.p.runbase[tid]       = l0 ? atomicAdd(&gcursor[tid], l0)       : 0;
            sh.p.runbase[tid + 256] = l1 ? atomicAdd(&gcursor[tid + 256], l1) : 0;
        }
        __syncthreads();

        for (int i = tid; i < nloc; i += 256) {      // contiguous run writes
            int b = sh.p.stb[i];
            es[(size_t)b * cap + sh.p.runbase[b] + (i - sh.p.xscan[b])] = sh.p.stage[i];
        }
        return;
    }

    // ---------- GEMM ----------
    const int row0 = (blockIdx.x - pblocks) * 64;
    {   // copy pre-swizzled W1 fragments (16 KB), conflict-free
        const float4* wg4 = (const float4*)wfg;
        float4* wl4 = (float4*)&sh.g.wf[0][0][0][0];
        #pragma unroll
        for (int i = 0; i < 4; i++) wl4[tid + i*256] = wg4[tid + i*256];
    }
    {   // stage x tile -> bf16
        const float4* x4 = (const float4*)x;
        #pragma unroll
        for (int i = 0; i < 8; i++) {
            int idx = tid + i*256;
            int r = idx >> 5, kc = idx & 31;
            int gr = row0 + r;
            float4 v = make_float4(0.f,0.f,0.f,0.f);
            if (gr < N) v = x4[gr*32 + kc];
            ushort4 o;
            o.x = f2bf(v.x); o.y = f2bf(v.y); o.z = f2bf(v.z); o.w = f2bf(v.w);
            *(ushort4*)&sh.g.xs[r][kc*4] = o;
        }
    }
    __syncthreads();

    const int wave = tid >> 6, lane = tid & 63;
    const int m = lane & 15, quad = lane >> 4;
    const int rw = wave * 16;

    floatx4 acc[4] = {(floatx4)(0.f), (floatx4)(0.f), (floatx4)(0.f), (floatx4)(0.f)};
    #pragma unroll
    for (int step = 0; step < 4; step++) {
        short8 a = *(const short8*)&sh.g.xs[rw + m][step*32 + quad*8];
        #pragma unroll
        for (int nt = 0; nt < 4; nt++) {
            short8 b = *(const short8*)&sh.g.wf[nt][step][lane][0];
            acc[nt] = __builtin_amdgcn_mfma_f32_16x16x32_bf16(a, b, acc[nt], 0, 0, 0);
        }
    }
    #pragma unroll
    for (int nt = 0; nt < 4; nt++) {
        #pragma unroll
        for (int r = 0; r < 4; r++) {
            int gr = row0 + rw + quad*4 + r;
            if (gr < N) h1[(size_t)gr*64 + nt*16 + m] = f2bf(acc[nt][r]);
        }
    }
}

// ------- sg1: FUSED per-bucket counting sort (in LDS) + gather1 + layer2 ----
__global__ __launch_bounds__(512, 4) void sg1_kernel(
    const u16* __restrict__ h1, const int2* __restrict__ es,
    const int* __restrict__ gcursor, int2* __restrict__ es2,
    int2* __restrict__ off2, const float* __restrict__ b1,
    const float* __restrict__ W2, u16* __restrict__ h2, int N, int cap)
{
    __shared__ int2 sorted[CAPC];                     // 36.9 KB bucket edges
    __shared__ __align__(16) u16 ts[8][16][72];       // 18.4 KB (per-wave rows)
    __shared__ __align__(16) u16 wf2[2][2][64][8];    // [ntile][step][lane][j]
    __shared__ float b1s[64];
    __shared__ int hist[256], exs[256], cur[256];
    const int t = threadIdx.x;
    const int b = blockIdx.x;
    const int e0 = b * cap;
    const int len = min(gcursor[b], CAPC);

    {   // stage W2 (512 float4, one per thread) -> bf16 B-fragments, + b1
        const float4* s4 = (const float4*)W2;
        float4 v = s4[t];
        int k = t >> 3, n4 = (t & 7) * 4;
        int step = k >> 5, quad = (k >> 3) & 3, j = k & 7;
        #pragma unroll
        for (int c = 0; c < 4; c++) {
            int n = n4 + c;
            wf2[n >> 4][step][quad*16 + (n & 15)][j] = f2bf(F4C(v, c));
        }
        if (t < 16) ((float4*)b1s)[t] = ((const float4*)b1)[t];
        if (t < 256) hist[t] = 0;
    }
    __syncthreads();

    // ---- phase 1: load bucket -> regs, hist by low byte ----
    int2 re[9]; int rk[9];
    #pragma unroll
    for (int k = 0; k < 9; k++) {
        int i = t + k * 512;
        if (i < len) {
            re[k] = es[e0 + i];
            rk[k] = (int)(((unsigned)re[k].x) >> 24);
            atomicAdd(&hist[rk[k]], 1);
        } else rk[k] = -1;
    }
    __syncthreads();

    int v = 0;
    if (t < 256) { v = hist[t]; cur[t] = v; }         // cur as scan buffer
    __syncthreads();
    for (int o = 1; o < 256; o <<= 1) {
        int add = 0;
        if (t < 256 && t >= o) add = cur[t - o];
        __syncthreads();
        if (t < 256) cur[t] += add;
        __syncthreads();
    }
    if (t < 256) {
        int ex = cur[t] - v;                          // exclusive scan
        exs[t] = ex;
        cur[t] = ex;                                  // scatter cursor
        int g = b * 256 + t;
        if (g < N) off2[g] = make_int2(e0 + ex, e0 + ex + v);
    }
    __syncthreads();

    #pragma unroll
    for (int k = 0; k < 9; k++)                       // scatter -> LDS sorted
        if (rk[k] >= 0) sorted[atomicAdd(&cur[rk[k]], 1)] = re[k];
    __syncthreads();

    for (int i = t; i < len; i += 512)                // coalesced es2 writeback
        es2[e0 + i] = sorted[i];

    // ---- phase 2: gather h1 over LDS-sorted edges; 8 waves x 32 nodes ----
    const int wave = t >> 6, lane = t & 63;
    const int h = lane >> 4, fl = lane & 15;          // slot 0..3, ch-group 0..15
    const uint2* h1v = (const uint2*)h1;   // h1 row = 16 uint2 (64 bf16, 128B)
    uint* tsu = (uint*)&ts[wave][0][0];    // this wave's 16 rows of 36 uints

    #pragma unroll 1
    for (int half = 0; half < 2; half++) {
        const int n0 = wave * 32 + half * 16;         // node offset in bucket
        #pragma unroll 1
        for (int j = 0; j < 8; j++) {                 // node pair (j, j+8)
            const int nA = n0 + j, nB = n0 + j + 8;
            const int pbegA = exs[nA], pendA = pbegA + hist[nA];
            const int pbegB = exs[nB], pendB = pbegB + hist[nB];
            const int clA = max(pendA - 1, 0), clB = max(pendB - 1, 0);
            float a0 = 0.f, a1 = 0.f, a2 = 0.f, a3 = 0.f;
            float c0 = 0.f, c1 = 0.f, c2 = 0.f, c3 = 0.f;
            int pA = pbegA, pB = pbegB;
            #pragma unroll 1
            while (pA < pendA || pB < pendB) {        // 16+16 edges, 8 gathers
                const int iA0 = pA + h,     iA1 = pA + 4 + h;
                const int iA2 = pA + 8 + h, iA3 = pA + 12 + h;
                const int iB0 = pB + h,     iB1 = pB + 4 + h;
                const int iB2 = pB + 8 + h, iB3 = pB + 12 + h;
                int2 eA0 = sorted[min(iA0, clA)];
                int2 eA1 = sorted[min(iA1, clA)];
                int2 eA2 = sorted[min(iA2, clA)];
                int2 eA3 = sorted[min(iA3, clA)];
                int2 eB0 = sorted[min(iB0, clB)];
                int2 eB1 = sorted[min(iB1, clB)];
                int2 eB2 = sorted[min(iB2, clB)];
                int2 eB3 = sorted[min(iB3, clB)];
                uint2 vA0 = h1v[(size_t)(eA0.x & 0xFFFFFF) * 16 + fl];
                uint2 vA1 = h1v[(size_t)(eA1.x & 0xFFFFFF) * 16 + fl];
                uint2 vA2 = h1v[(size_t)(eA2.x & 0xFFFFFF) * 16 + fl];
                uint2 vA3 = h1v[(size_t)(eA3.x & 0xFFFFFF) * 16 + fl];
                uint2 vB0 = h1v[(size_t)(eB0.x & 0xFFFFFF) * 16 + fl];
                uint2 vB1 = h1v[(size_t)(eB1.x & 0xFFFFFF) * 16 + fl];
                uint2 vB2 = h1v[(size_t)(eB2.x & 0xFFFFFF) * 16 + fl];
                uint2 vB3 = h1v[(size_t)(eB3.x & 0xFFFFFF) * 16 + fl];
                float wA0 = (iA0 < pendA) ? __int_as_float(eA0.y) : 0.f;
                float wA1 = (iA1 < pendA) ? __int_as_float(eA1.y) : 0.f;
                float wA2 = (iA2 < pendA) ? __int_as_float(eA2.y) : 0.f;
                float wA3 = (iA3 < pendA) ? __int_as_float(eA3.y) : 0.f;
                float wB0 = (iB0 < pendB) ? __int_as_float(eB0.y) : 0.f;
                float wB1 = (iB1 < pendB) ? __int_as_float(eB1.y) : 0.f;
                float wB2 = (iB2 < pendB) ? __int_as_float(eB2.y) : 0.f;
                float wB3 = (iB3 < pendB) ? __int_as_float(eB3.y) : 0.f;
                a0 += __uint_as_float(vA0.x << 16) * wA0 + __uint_as_float(vA1.x << 16) * wA1
                    + __uint_as_float(vA2.x << 16) * wA2 + __uint_as_float(vA3.x << 16) * wA3;
                a1 += __uint_as_float(vA0.x & 0xFFFF0000u) * wA0 + __uint_as_float(vA1.x & 0xFFFF0000u) * wA1
                    + __uint_as_float(vA2.x & 0xFFFF0000u) * wA2 + __uint_as_float(vA3.x & 0xFFFF0000u) * wA3;
                a2 += __uint_as_float(vA0.y << 16) * wA0 + __uint_as_float(vA1.y << 16) * wA1
                    + __uint_as_float(vA2.y << 16) * wA2 + __uint_as_float(vA3.y << 16) * wA3;
                a3 += __uint_as_float(vA0.y & 0xFFFF0000u) * wA0 + __uint_as_float(vA1.y & 0xFFFF0000u) * wA1
                    + __uint_as_float(vA2.y & 0xFFFF0000u) * wA2 + __uint_as_float(vA3.y & 0xFFFF0000u) * wA3;
                c0 += __uint_as_float(vB0.x << 16) * wB0 + __uint_as_float(vB1.x << 16) * wB1
                    + __uint_as_float(vB2.x << 16) * wB2 + __uint_as_float(vB3.x << 16) * wB3;
                c1 += __uint_as_float(vB0.x & 0xFFFF0000u) * wB0 + __uint_as_float(vB1.x & 0xFFFF0000u) * wB1
                    + __uint_as_float(vB2.x & 0xFFFF0000u) * wB2 + __uint_as_float(vB3.x & 0xFFFF0000u) * wB3;
                c2 += __uint_as_float(vB0.y << 16) * wB0 + __uint_as_float(vB1.y << 16) * wB1
                    + __uint_as_float(vB2.y << 16) * wB2 + __uint_as_float(vB3.y << 16) * wB3;
                c3 += __uint_as_float(vB0.y & 0xFFFF0000u) * wB0 + __uint_as_float(vB1.y & 0xFFFF0000u) * wB1
                    + __uint_as_float(vB2.y & 0xFFFF0000u) * wB2 + __uint_as_float(vB3.y & 0xFFFF0000u) * wB3;
                pA += 16; pB += 16;
            }
            a0 += __shfl_xor(a0, 16, 64); a1 += __shfl_xor(a1, 16, 64);
            a2 += __shfl_xor(a2, 16, 64); a3 += __shfl_xor(a3, 16, 64);
            a0 += __shfl_xor(a0, 32, 64); a1 += __shfl_xor(a1, 32, 64);
            a2 += __shfl_xor(a2, 32, 64); a3 += __shfl_xor(a3, 32, 64);
            c0 += __shfl_xor(c0, 16, 64); c1 += __shfl_xor(c1, 16, 64);
            c2 += __shfl_xor(c2, 16, 64); c3 += __shfl_xor(c3, 16, 64);
            c0 += __shfl_xor(c0, 32, 64); c1 += __shfl_xor(c1, 32, 64);
            c2 += __shfl_xor(c2, 32, 64); c3 += __shfl_xor(c3, 32, 64);
            if (h == 0) {
                uint t0 = (uint)f2bf(fmaxf(a0 + b1s[4*fl],     0.f))
                        | ((uint)f2bf(fmaxf(a1 + b1s[4*fl + 1], 0.f)) << 16);
                uint t1 = (uint)f2bf(fmaxf(a2 + b1s[4*fl + 2], 0.f))
                        | ((uint)f2bf(fmaxf(a3 + b1s[4*fl + 3], 0.f)) << 16);
                *(uint2*)&tsu[j * 36 + 2*fl] = make_uint2(t0, t1);
                uint t2 = (uint)f2bf(fmaxf(c0 + b1s[4*fl],     0.f))
                        | ((uint)f2bf(fmaxf(c1 + b1s[4*fl + 1], 0.f)) << 16);
                uint t3 = (uint)f2bf(fmaxf(c2 + b1s[4*fl + 2], 0.f))
                        | ((uint)f2bf(fmaxf(c3 + b1s[4*fl + 3], 0.f)) << 16);
                *(uint2*)&tsu[(j + 8) * 36 + 2*fl] = make_uint2(t2, t3);
            }
        }

        // layer2 MFMA on this wave's 16 rows (intra-wave LDS dep, in-order)
        const int m = lane & 15, quad = lane >> 4;
        floatx4 acc[2] = {(floatx4)(0.f), (floatx4)(0.f)};
        #pragma unroll
        for (int step = 0; step < 2; step++) {
            short8 a = *(const short8*)&ts[wave][m][step*32 + quad*8];
            #pragma unroll
            for (int nt = 0; nt < 2; nt++) {
                short8 bb = *(const short8*)&wf2[nt][step][lane][0];
                acc[nt] = __builtin_amdgcn_mfma_f32_16x16x32_bf16(a, bb, acc[nt], 0, 0, 0);
            }
        }
        #pragma unroll
        for (int nt = 0; nt < 2; nt++) {
            #pragma unroll
            for (int r = 0; r < 4; r++) {
                int g = b * 256 + n0 + quad*4 + r;
                if (g < N) h2[(size_t)g*32 + nt*16 + m] = f2bf(acc[nt][r]);
            }
        }
    }
}

// ------- gather2: 16 nodes/wave, LDS edge staging + node-pair interleave,
//   8 lanes/row dwordx2, 2+2 loads per iter --------------------------------
__global__ __launch_bounds__(256, 4) void gather2_kernel(
    const u16* __restrict__ h2, const int2* __restrict__ es,
    const int2* __restrict__ off2, const float* __restrict__ b2,
    float* __restrict__ out, int N)
{
    __shared__ int2 eb[4][ECAP];
    const int tid = threadIdx.x;
    const int wave = tid >> 6, lane = tid & 63;
    const int g = lane >> 3, fl = lane & 7;           // slot 0..7, ch-group 0..7
    const int node0 = blockIdx.x * 64 + wave * 16;
    const uint2* h2v = (const uint2*)h2;   // h2 row = 8 uint2 (32 bf16, 64B)

    const int2 sg = off2[min(node0 + (lane & 15), N - 1)];
    const int beg = __builtin_amdgcn_readfirstlane(sg.x);
    const int end = __builtin_amdgcn_readlane(sg.y, 15);
    const int len = end - beg;
    const float4 bb = ((const float4*)b2)[fl];

    if (len <= ECAP) {
        for (int k = lane; k < len; k += 64) eb[wave][k] = es[beg + k];

        #pragma unroll 1
        for (int j = 0; j < 8; j++) {                 // node pair (j, j+8)
            const int pbegA = __builtin_amdgcn_readlane(sg.x, j) - beg;
            const int pendA = __builtin_amdgcn_readlane(sg.y, j) - beg;
            const int pbegB = __builtin_amdgcn_readlane(sg.x, j + 8) - beg;
            const int pendB = __builtin_amdgcn_readlane(sg.y, j + 8) - beg;
            const int clA = max(pendA - 1, 0), clB = max(pendB - 1, 0);
            float a0 = 0.f, a1 = 0.f, a2 = 0.f, a3 = 0.f;
            float c0 = 0.f, c1 = 0.f, c2 = 0.f, c3 = 0.f;
            int pA = pbegA, pB = pbegB;
            #pragma unroll 1
            while (pA < pendA || pB < pendB) {        // 16+16 edges, 4 gathers
                const int iA0 = pA + g, iA1 = pA + 8 + g;
                const int iB0 = pB + g, iB1 = pB + 8 + g;
                int2 eA0 = eb[wave][min(iA0, clA)];
                int2 eA1 = eb[wave][min(iA1, clA)];
                int2 eB0 = eb[wave][min(iB0, clB)];
                int2 eB1 = eb[wave][min(iB1, clB)];
                uint2 vA0 = h2v[(size_t)(eA0.x & 0xFFFFFF) * 8 + fl];
                uint2 vA1 = h2v[(size_t)(eA1.x & 0xFFFFFF) * 8 + fl];
                uint2 vB0 = h2v[(size_t)(eB0.x & 0xFFFFFF) * 8 + fl];
                uint2 vB1 = h2v[(size_t)(eB1.x & 0xFFFFFF) * 8 + fl];
                float wA0 = (iA0 < pendA) ? __int_as_float(eA0.y) : 0.f;
                float wA1 = (iA1 < pendA) ? __int_as_float(eA1.y) : 0.f;
                float wB0 = (iB0 < pendB) ? __int_as_float(eB0.y) : 0.f;
                float wB1 = (iB1 < pendB) ? __int_as_float(eB1.y) : 0.f;
                a0 += __uint_as_float(vA0.x << 16) * wA0 + __uint_as_float(vA1.x << 16) * wA1;
                a1 += __uint_as_float(vA0.x & 0xFFFF0000u) * wA0 + __uint_as_float(vA1.x & 0xFFFF0000u) * wA1;
                a2 += __uint_as_float(vA0.y << 16) * wA0 + __uint_as_float(vA1.y << 16) * wA1;
                a3 += __uint_as_float(vA0.y & 0xFFFF0000u) * wA0 + __uint_as_float(vA1.y & 0xFFFF0000u) * wA1;
                c0 += __uint_as_float(vB0.x << 16) * wB0 + __uint_as_float(vB1.x << 16) * wB1;
                c1 += __uint_as_float(vB0.x & 0xFFFF0000u) * wB0 + __uint_as_float(vB1.x & 0xFFFF0000u) * wB1;
                c2 += __uint_as_float(vB0.y << 16) * wB0 + __uint_as_float(vB1.y << 16) * wB1;
                c3 += __uint_as_float(vB0.y & 0xFFFF0000u) * wB0 + __uint_as_float(vB1.y & 0xFFFF0000u) * wB1;
                pA += 16; pB += 16;
            }
            a0 += __shfl_xor(a0, 8, 64);  a1 += __shfl_xor(a1, 8, 64);
            a2 += __shfl_xor(a2, 8, 64);  a3 += __shfl_xor(a3, 8, 64);
            a0 += __shfl_xor(a0, 16, 64); a1 += __shfl_xor(a1, 16, 64);
            a2 += __shfl_xor(a2, 16, 64); a3 += __shfl_xor(a3, 16, 64);
            a0 += __shfl_xor(a0, 32, 64); a1 += __shfl_xor(a1, 32, 64);
            a2 += __shfl_xor(a2, 32, 64); a3 += __shfl_xor(a3, 32, 64);
            c0 += __shfl_xor(c0, 8, 64);  c1 += __shfl_xor(c1, 8, 64);
            c2 += __shfl_xor(c2, 8, 64);  c3 += __shfl_xor(c3, 8, 64);
            c0 += __shfl_xor(c0, 16, 64); c1 += __shfl_xor(c1, 16, 64);
            c2 += __shfl_xor(c2, 16, 64); c3 += __shfl_xor(c3, 16, 64);
            c0 += __shfl_xor(c0, 32, 64); c1 += __shfl_xor(c1, 32, 64);
            c2 += __shfl_xor(c2, 32, 64); c3 += __shfl_xor(c3, 32, 64);
            const int dA = node0 + j, dB = node0 + j + 8;
            if (g == 0 && dA < N)
                *(float4*)&out[(size_t)dA * 32 + 4 * fl] =
                    make_float4(a0 + bb.x, a1 + bb.y, a2 + bb.z, a3 + bb.w);
            if (g == 0 && dB < N)
                *(float4*)&out[(size_t)dB * 32 + 4 * fl] =
                    make_float4(c0 + bb.x, c1 + bb.y, c2 + bb.z, c3 + bb.w);
        }
    } else {
        #pragma unroll 1
        for (int i = 0; i < 16; i++) {
            const int pbeg = __builtin_amdgcn_readlane(sg.x, i);
            const int pend = __builtin_amdgcn_readlane(sg.y, i);
            const int cl = max(pend - 1, 0);
            float a0 = 0.f, a1 = 0.f, a2 = 0.f, a3 = 0.f;
            #pragma unroll 1
            for (int p = pbeg; p < pend; p += 32) {
                const int i0 = p + g, i1 = p + 8 + g, i2 = p + 16 + g, i3 = p + 24 + g;
                int2 e0 = es[min(i0, cl)];
                int2 e1 = es[min(i1, cl)];
                int2 e2 = es[min(i2, cl)];
                int2 e3 = es[min(i3, cl)];
                uint2 v0 = h2v[(size_t)(e0.x & 0xFFFFFF) * 8 + fl];
                uint2 v1 = h2v[(size_t)(e1.x & 0xFFFFFF) * 8 + fl];
                uint2 v2 = h2v[(size_t)(e2.x & 0xFFFFFF) * 8 + fl];
                uint2 v3 = h2v[(size_t)(e3.x & 0xFFFFFF) * 8 + fl];
                float w0 = (i0 < pend) ? __int_as_float(e0.y) : 0.f;
                float w1 = (i1 < pend) ? __int_as_float(e1.y) : 0.f;
                float w2 = (i2 < pend) ? __int_as_float(e2.y) : 0.f;
                float w3 = (i3 < pend) ? __int_as_float(e3.y) : 0.f;
                a0 += __uint_as_float(v0.x << 16) * w0 + __uint_as_float(v1.x << 16) * w1
                    + __uint_as_float(v2.x << 16) * w2 + __uint_as_float(v3.x << 16) * w3;
                a1 += __uint_as_float(v0.x & 0xFFFF0000u) * w0 + __uint_as_float(v1.x & 0xFFFF0000u) * w1
                    + __uint_as_float(v2.x & 0xFFFF0000u) * w2 + __uint_as_float(v3.x & 0xFFFF0000u) * w3;
                a2 += __uint_as_float(v0.y << 16) * w0 + __uint_as_float(v1.y << 16) * w1
                    + __uint_as_float(v2.y << 16) * w2 + __uint_as_float(v3.y << 16) * w3;
                a3 += __uint_as_float(v0.y & 0xFFFF0000u) * w0 + __uint_as_float(v1.y & 0xFFFF0000u) * w1
                    + __uint_as_float(v2.y & 0xFFFF0000u) * w2 + __uint_as_float(v3.y & 0xFFFF0000u) * w3;
            }
            a0 += __shfl_xor(a0, 8, 64);  a1 += __shfl_xor(a1, 8, 64);
            a2 += __shfl_xor(a2, 8, 64);  a3 += __shfl_xor(a3, 8, 64);
            a0 += __shfl_xor(a0, 16, 64); a1 += __shfl_xor(a1, 16, 64);
            a2 += __shfl_xor(a2, 16, 64); a3 += __shfl_xor(a3, 16, 64);
            a0 += __shfl_xor(a0, 32, 64); a1 += __shfl_xor(a1, 32, 64);
            a2 += __shfl_xor(a2, 32, 64); a3 += __shfl_xor(a3, 32, 64);
            const int d = node0 + i;
            if (g == 0 && d < N)
                *(float4*)&out[(size_t)d * 32 + 4 * fl] =
                    make_float4(a0 + bb.x, a1 + bb.y, a2 + bb.z, a3 + bb.w);
        }
    }
}

extern "C" void kernel_launch(void* const* d_in, const int* in_sizes, int n_in,
                              void* d_out, int out_size, void* d_ws, size_t ws_size,
                              hipStream_t stream)
{
    const float* x   = (const float*)d_in[0];
    const int*  esrc = (const int*)d_in[1];
    const int*  edst = (const int*)d_in[2];
    const float* ew  = (const float*)d_in[3];
    const float* W1  = (const float*)d_in[4];
    const float* b1  = (const float*)d_in[5];
    const float* W2  = (const float*)d_in[6];
    const float* b2  = (const float*)d_in[7];
    float* out = (float*)d_out;

    const int N = in_sizes[0] / 128;   // 100000
    const int E = in_sizes[1];         // 1600000
    const int nb = (N + 255) >> 8;     // 391 buckets

    // slack bucket capacity: mean + ~8 sigma, 16-aligned (= CAPC for these shapes)
    const int mean = (E + nb - 1) / nb;
    int s = 1; while (s * s < mean) s++;                  // ceil sqrt
    int cap = (mean + 8 * s + 15) & ~15;                  // 4608
    if (cap > CAPC) cap = CAPC;

    char* base = (char*)d_ws;
    size_t o = 0;
    auto alloc = [&](size_t bytes) { char* p = base + o; o = (o + bytes + 255) & ~(size_t)255; return p; };
    u16*  h1      = (u16*) alloc((size_t)N * 64 * 2);
    u16*  h2      = (u16*) alloc((size_t)N * 32 * 2);
    int2* es      = (int2*)alloc((size_t)nb * cap * 8);
    int2* es2     = (int2*)alloc((size_t)nb * cap * 8);
    int2* off2    = (int2*)alloc((size_t)N * 8);
    int*  gcursor = (int*) alloc(512 * 4);
    u16*  wfg     = (u16*) alloc(8192 * 2);               // W1 frags, 16 KB

    const int pblocks = (E + CHUNK - 1) / CHUNK;   // 782 partition blocks
    const int gblocks = (N + 63) / 64;             // 1563 gemm blocks

    init_kernel<<<8, 256, 0, stream>>>(W1, wfg, gcursor);
    g1p_kernel<<<pblocks + gblocks, 256, 0, stream>>>(
        x, wfg, h1, N, esrc, edst, ew, gcursor, es, E, cap, pblocks);
    sg1_kernel<<<nb, 512, 0, stream>>>(h1, es, gcursor, es2, off2, b1, W2, h2, N, cap);
    gather2_kernel<<<(N + 63) / 64, 256, 0, stream>>>(h2, es2, off2, b2, out, N);
}

// Round 9
// 216.022 us; speedup vs baseline: 1.0534x; 1.0140x over previous
//
#include <hip/hip_runtime.h>
#include <hip/hip_bf16.h>

// GCN 2-layer, slack-bucket dst-radix-sort + batched wave gathers:
//   init: zero gcursor + pre-swizzle W1 -> bf16 fragment order (wfg)
//   fused dispatch: blocks [0,pblocks) partition edges into slack bucket
//     regions (hist -> scan -> LDS group -> coalesced run writes);
//     blocks [pblocks,..) do h1 = bf16(bf16(x) @ bf16(W1)) via MFMA
//   sg1 (FUSED sort+gather1, SPLIT): TWO blocks per bucket (512 thr).
//     Each hists the full bucket, sorts only its node-half (keys 0-127 /
//     128-255) into LDS, writes its es2 half + off2 (h==0); then 8 waves
//     x 16 nodes gather h1 from LDS-sorted edges (node-pair interleave,
//     16 lanes/row dwordx2); layer2 (relu(+b1) @ W2) via MFMA -> h2
//   gather2 (LDS edge staging + node-pair interleave): 8 lanes/row dwordx2

typedef unsigned short u16;
typedef unsigned int uint;
typedef short short8 __attribute__((ext_vector_type(8)));
typedef float floatx4 __attribute__((ext_vector_type(4)));

static __device__ __forceinline__ u16 f2bf(float f) {
    unsigned int u = __float_as_uint(f);
    return (u16)((u + 0x7fff + ((u >> 16) & 1)) >> 16);   // RNE
}

#define F4C(v, j) ((j)==0?(v).x:((j)==1?(v).y:((j)==2?(v).z:(v).w)))
#define CHUNK 2048
#define CAPC 4608   // bucket capacity (mean 4096 + 8 sigma, 16-aligned) = host cap
#define SCAPH 2816  // node-half LDS capacity (mean 2048, +24 sigma)
#define ECAP 384    // gather2 per-wave LDS edge-buffer capacity

// ------- init: zero gcursor + W1 (128x64 f32) -> bf16 B-fragment order -----
__global__ __launch_bounds__(256) void init_kernel(
    const float* __restrict__ W1, u16* __restrict__ wfg, int* __restrict__ gcursor)
{
    const int idx = blockIdx.x * 256 + threadIdx.x;       // grid 8x256 = 2048
    if (idx < 512) gcursor[idx] = 0;
    const float4 v = ((const float4*)W1)[idx];
    const int k = idx >> 4, n4 = (idx & 15) * 4;
    const int step = k >> 5, klane = (k >> 3) & 3, j = k & 7;
    #pragma unroll
    for (int c = 0; c < 4; c++) {
        int n = n4 + c;
        wfg[(((n >> 4) * 4 + step) * 64 + klane * 16 + (n & 15)) * 8 + j] = f2bf(F4C(v, c));
    }
}

// ------- fused: partition (blocks 0..pblocks-1) + GEMM h1=x@W1 (rest) -------
// edge entry: x = src | (dst&255)<<24 ; y = w bits
union __align__(16) SharedU {
    struct {                                   // GEMM part (33.8 KB)
        u16 xs[64][136];
        u16 wf[4][4][64][8];                   // [ntile][step][lane][j]
    } g;
    struct {                                   // partition part (30.7 KB)
        int2 stage[CHUNK];                     // 16 KB
        u16  stb[CHUNK];                       // 4 KB
        int  hist[512], sc[512], xscan[512], place[512], runbase[512];
    } p;
};

__global__ __launch_bounds__(256, 4) void g1p_kernel(
    const float* __restrict__ x, const u16* __restrict__ wfg,
    u16* __restrict__ h1, int N,
    const int* __restrict__ src, const int* __restrict__ dst,
    const float* __restrict__ w, int* __restrict__ gcursor,
    int2* __restrict__ es, int E, int cap, int pblocks)
{
    __shared__ SharedU sh;
    const int tid = threadIdx.x;

    if (blockIdx.x < pblocks) {            // ---------- partition ----------
        const int base = blockIdx.x * CHUNK;
        const int nloc = min(CHUNK, E - base);

        sh.p.hist[tid] = 0; sh.p.hist[tid + 256] = 0;
        __syncthreads();
        for (int i = tid; i < nloc; i += 256)
            atomicAdd(&sh.p.hist[dst[base + i] >> 8], 1);
        __syncthreads();

        sh.p.sc[tid] = sh.p.hist[tid];
        sh.p.sc[tid + 256] = sh.p.hist[tid + 256];
        __syncthreads();
        for (int o = 1; o < 512; o <<= 1) {          // inclusive scan, 512 wide
            int v0 = (tid >= o) ? sh.p.sc[tid - o] : 0;
            int v1 = (tid + 256 >= o) ? sh.p.sc[tid + 256 - o] : 0;
            __syncthreads();
            sh.p.sc[tid] += v0;
            sh.p.sc[tid + 256] += v1;
            __syncthreads();
        }
        sh.p.xscan[tid] = sh.p.sc[tid] - sh.p.hist[tid];
        sh.p.xscan[tid + 256] = sh.p.sc[tid + 256] - sh.p.hist[tid + 256];
        sh.p.place[tid] = sh.p.xscan[tid];
        sh.p.place[tid + 256] = sh.p.xscan[tid + 256];
        __syncthreads();

        for (int i = tid; i < nloc; i += 256) {      // group by bucket in LDS
            int d = dst[base + i];
            int b = d >> 8;
            int pos = atomicAdd(&sh.p.place[b], 1);
            sh.p.stage[pos] = make_int2(src[base + i] | ((d & 255) << 24),
                                        __float_as_int(w[base + i]));
            sh.p.stb[pos] = (u16)b;
        }
        __syncthreads();

        {   // reserve runs in slack regions
            int l0 = sh.p.hist[tid], l1 = sh.p.hist[tid + 256];
            sh.p.runbase[tid]       = l0 ? atomicAdd(&gcursor[tid], l0)       : 0;
            sh.p.runbase[tid + 256] = l1 ? atomicAdd(&gcursor[tid + 256], l1) : 0;
        }
        __syncthreads();

        for (int i = tid; i < nloc; i += 256) {      // contiguous run writes
            int b = sh.p.stb[i];
            es[(size_t)b * cap + sh.p.runbase[b] + (i - sh.p.xscan[b])] = sh.p.stage[i];
        }
        return;
    }

    // ---------- GEMM ----------
    const int row0 = (blockIdx.x - pblocks) * 64;
    {   // copy pre-swizzled W1 fragments (16 KB), conflict-free
        const float4* wg4 = (const float4*)wfg;
        float4* wl4 = (float4*)&sh.g.wf[0][0][0][0];
        #pragma unroll
        for (int i = 0; i < 4; i++) wl4[tid + i*256] = wg4[tid + i*256];
    }
    {   // stage x tile -> bf16
        const float4* x4 = (const float4*)x;
        #pragma unroll
        for (int i = 0; i < 8; i++) {
            int idx = tid + i*256;
            int r = idx >> 5, kc = idx & 31;
            int gr = row0 + r;
            float4 v = make_float4(0.f,0.f,0.f,0.f);
            if (gr < N) v = x4[gr*32 + kc];
            ushort4 o;
            o.x = f2bf(v.x); o.y = f2bf(v.y); o.z = f2bf(v.z); o.w = f2bf(v.w);
            *(ushort4*)&sh.g.xs[r][kc*4] = o;
        }
    }
    __syncthreads();

    const int wave = tid >> 6, lane = tid & 63;
    const int m = lane & 15, quad = lane >> 4;
    const int rw = wave * 16;

    floatx4 acc[4] = {(floatx4)(0.f), (floatx4)(0.f), (floatx4)(0.f), (floatx4)(0.f)};
    #pragma unroll
    for (int step = 0; step < 4; step++) {
        short8 a = *(const short8*)&sh.g.xs[rw + m][step*32 + quad*8];
        #pragma unroll
        for (int nt = 0; nt < 4; nt++) {
            short8 b = *(const short8*)&sh.g.wf[nt][step][lane][0];
            acc[nt] = __builtin_amdgcn_mfma_f32_16x16x32_bf16(a, b, acc[nt], 0, 0, 0);
        }
    }
    #pragma unroll
    for (int nt = 0; nt < 4; nt++) {
        #pragma unroll
        for (int r = 0; r < 4; r++) {
            int gr = row0 + rw + quad*4 + r;
            if (gr < N) h1[(size_t)gr*64 + nt*16 + m] = f2bf(acc[nt][r]);
        }
    }
}

// ------- sg1 (split): 2 blocks/bucket. Full-bucket hist+scan; sort own
//   node-half into LDS; es2/off2 writeback; gather+layer2 for 128 nodes ----
__global__ __launch_bounds__(512, 6) void sg1_kernel(
    const u16* __restrict__ h1, const int2* __restrict__ es,
    const int* __restrict__ gcursor, int2* __restrict__ es2,
    int2* __restrict__ off2, const float* __restrict__ b1,
    const float* __restrict__ W2, u16* __restrict__ h2, int N, int cap)
{
    __shared__ int2 sortedH[SCAPH];                   // 22.5 KB node-half edges
    __shared__ __align__(16) u16 ts[8][16][72];       // 18.4 KB (per-wave rows)
    __shared__ __align__(16) u16 wf2[2][2][64][8];    // [ntile][step][lane][j]
    __shared__ float b1s[64];
    __shared__ int hist[256], exs[256], cur[256];
    const int t = threadIdx.x;
    const int b = blockIdx.x >> 1, hh = blockIdx.x & 1;
    const int e0 = b * cap;
    const int len = min(gcursor[b], cap);

    {   // stage W2 (512 float4, one per thread) -> bf16 B-fragments, + b1
        const float4* s4 = (const float4*)W2;
        float4 v = s4[t];
        int k = t >> 3, n4 = (t & 7) * 4;
        int step = k >> 5, quad = (k >> 3) & 3, j = k & 7;
        #pragma unroll
        for (int c = 0; c < 4; c++) {
            int n = n4 + c;
            wf2[n >> 4][step][quad*16 + (n & 15)][j] = f2bf(F4C(v, c));
        }
        if (t < 16) ((float4*)b1s)[t] = ((const float4*)b1)[t];
        if (t < 256) hist[t] = 0;
    }
    __syncthreads();

    // ---- phase 1: full bucket -> regs, hist by low byte ----
    int2 re[9]; int rk[9];
    #pragma unroll
    for (int k = 0; k < 9; k++) {
        int i = t + k * 512;
        if (i < len) {
            re[k] = es[e0 + i];
            rk[k] = (int)(((unsigned)re[k].x) >> 24);
            atomicAdd(&hist[rk[k]], 1);
        } else rk[k] = -1;
    }
    __syncthreads();

    int v = 0;
    if (t < 256) { v = hist[t]; cur[t] = v; }         // cur as scan buffer
    __syncthreads();
    for (int o = 1; o < 256; o <<= 1) {
        int add = 0;
        if (t < 256 && t >= o) add = cur[t - o];
        __syncthreads();
        if (t < 256) cur[t] += add;
        __syncthreads();
    }
    if (t < 256) {
        int ex = cur[t] - v;                          // exclusive scan
        exs[t] = ex;
        if (hh == 0) {
            int g = b * 256 + t;
            if (g < N) off2[g] = make_int2(e0 + ex, e0 + ex + v);
        }
    }
    __syncthreads();

    const int baseH = hh ? exs[128] : 0;
    const int halflen = hh ? (len - exs[128]) : exs[128];
    if (t < 256) cur[t] = exs[t] - baseH;             // scatter cursor (own half)
    __syncthreads();

    #pragma unroll
    for (int k = 0; k < 9; k++)                       // scatter own half -> LDS
        if (rk[k] >= 0 && (rk[k] >> 7) == hh) {
            int pos = atomicAdd(&cur[rk[k]], 1);
            sortedH[min(pos, SCAPH - 1)] = re[k];
        }
    __syncthreads();

    for (int i = t; i < halflen; i += 512)            // coalesced es2 writeback
        es2[e0 + baseH + i] = sortedH[i];

    // ---- phase 2: gather h1; 8 waves x 16 nodes (keys hh*128 + w*16 + j) ----
    const int wave = t >> 6, lane = t & 63;
    const int h = lane >> 4, fl = lane & 15;          // slot 0..3, ch-group 0..15
    const uint2* h1v = (const uint2*)h1;   // h1 row = 16 uint2 (64 bf16, 128B)
    uint* tsu = (uint*)&ts[wave][0][0];    // this wave's 16 rows of 36 uints
    const int k0 = hh * 128 + wave * 16;              // first key of this wave

    #pragma unroll 1
    for (int j = 0; j < 8; j++) {                     // node pair (j, j+8)
        const int nA = k0 + j, nB = k0 + j + 8;
        const int pbegA = exs[nA] - baseH, pendA = pbegA + hist[nA];
        const int pbegB = exs[nB] - baseH, pendB = pbegB + hist[nB];
        const int clA = max(pendA - 1, 0), clB = max(pendB - 1, 0);
        float a0 = 0.f, a1 = 0.f, a2 = 0.f, a3 = 0.f;
        float c0 = 0.f, c1 = 0.f, c2 = 0.f, c3 = 0.f;
        int pA = pbegA, pB = pbegB;
        #pragma unroll 1
        while (pA < pendA || pB < pendB) {            // 16+16 edges, 8 gathers
            const int iA0 = pA + h,     iA1 = pA + 4 + h;
            const int iA2 = pA + 8 + h, iA3 = pA + 12 + h;
            const int iB0 = pB + h,     iB1 = pB + 4 + h;
            const int iB2 = pB + 8 + h, iB3 = pB + 12 + h;
            int2 eA0 = sortedH[min(iA0, clA)];
            int2 eA1 = sortedH[min(iA1, clA)];
            int2 eA2 = sortedH[min(iA2, clA)];
            int2 eA3 = sortedH[min(iA3, clA)];
            int2 eB0 = sortedH[min(iB0, clB)];
            int2 eB1 = sortedH[min(iB1, clB)];
            int2 eB2 = sortedH[min(iB2, clB)];
            int2 eB3 = sortedH[min(iB3, clB)];
            uint2 vA0 = h1v[(size_t)(eA0.x & 0xFFFFFF) * 16 + fl];
            uint2 vA1 = h1v[(size_t)(eA1.x & 0xFFFFFF) * 16 + fl];
            uint2 vA2 = h1v[(size_t)(eA2.x & 0xFFFFFF) * 16 + fl];
            uint2 vA3 = h1v[(size_t)(eA3.x & 0xFFFFFF) * 16 + fl];
            uint2 vB0 = h1v[(size_t)(eB0.x & 0xFFFFFF) * 16 + fl];
            uint2 vB1 = h1v[(size_t)(eB1.x & 0xFFFFFF) * 16 + fl];
            uint2 vB2 = h1v[(size_t)(eB2.x & 0xFFFFFF) * 16 + fl];
            uint2 vB3 = h1v[(size_t)(eB3.x & 0xFFFFFF) * 16 + fl];
            float wA0 = (iA0 < pendA) ? __int_as_float(eA0.y) : 0.f;
            float wA1 = (iA1 < pendA) ? __int_as_float(eA1.y) : 0.f;
            float wA2 = (iA2 < pendA) ? __int_as_float(eA2.y) : 0.f;
            float wA3 = (iA3 < pendA) ? __int_as_float(eA3.y) : 0.f;
            float wB0 = (iB0 < pendB) ? __int_as_float(eB0.y) : 0.f;
            float wB1 = (iB1 < pendB) ? __int_as_float(eB1.y) : 0.f;
            float wB2 = (iB2 < pendB) ? __int_as_float(eB2.y) : 0.f;
            float wB3 = (iB3 < pendB) ? __int_as_float(eB3.y) : 0.f;
            a0 += __uint_as_float(vA0.x << 16) * wA0 + __uint_as_float(vA1.x << 16) * wA1
                + __uint_as_float(vA2.x << 16) * wA2 + __uint_as_float(vA3.x << 16) * wA3;
            a1 += __uint_as_float(vA0.x & 0xFFFF0000u) * wA0 + __uint_as_float(vA1.x & 0xFFFF0000u) * wA1
                + __uint_as_float(vA2.x & 0xFFFF0000u) * wA2 + __uint_as_float(vA3.x & 0xFFFF0000u) * wA3;
            a2 += __uint_as_float(vA0.y << 16) * wA0 + __uint_as_float(vA1.y << 16) * wA1
                + __uint_as_float(vA2.y << 16) * wA2 + __uint_as_float(vA3.y << 16) * wA3;
            a3 += __uint_as_float(vA0.y & 0xFFFF0000u) * wA0 + __uint_as_float(vA1.y & 0xFFFF0000u) * wA1
                + __uint_as_float(vA2.y & 0xFFFF0000u) * wA2 + __uint_as_float(vA3.y & 0xFFFF0000u) * wA3;
            c0 += __uint_as_float(vB0.x << 16) * wB0 + __uint_as_float(vB1.x << 16) * wB1
                + __uint_as_float(vB2.x << 16) * wB2 + __uint_as_float(vB3.x << 16) * wB3;
            c1 += __uint_as_float(vB0.x & 0xFFFF0000u) * wB0 + __uint_as_float(vB1.x & 0xFFFF0000u) * wB1
                + __uint_as_float(vB2.x & 0xFFFF0000u) * wB2 + __uint_as_float(vB3.x & 0xFFFF0000u) * wB3;
            c2 += __uint_as_float(vB0.y << 16) * wB0 + __uint_as_float(vB1.y << 16) * wB1
                + __uint_as_float(vB2.y << 16) * wB2 + __uint_as_float(vB3.y << 16) * wB3;
            c3 += __uint_as_float(vB0.y & 0xFFFF0000u) * wB0 + __uint_as_float(vB1.y & 0xFFFF0000u) * wB1
                + __uint_as_float(vB2.y & 0xFFFF0000u) * wB2 + __uint_as_float(vB3.y & 0xFFFF0000u) * wB3;
            pA += 16; pB += 16;
        }
        a0 += __shfl_xor(a0, 16, 64); a1 += __shfl_xor(a1, 16, 64);
        a2 += __shfl_xor(a2, 16, 64); a3 += __shfl_xor(a3, 16, 64);
        a0 += __shfl_xor(a0, 32, 64); a1 += __shfl_xor(a1, 32, 64);
        a2 += __shfl_xor(a2, 32, 64); a3 += __shfl_xor(a3, 32, 64);
        c0 += __shfl_xor(c0, 16, 64); c1 += __shfl_xor(c1, 16, 64);
        c2 += __shfl_xor(c2, 16, 64); c3 += __shfl_xor(c3, 16, 64);
        c0 += __shfl_xor(c0, 32, 64); c1 += __shfl_xor(c1, 32, 64);
        c2 += __shfl_xor(c2, 32, 64); c3 += __shfl_xor(c3, 32, 64);
        if (h == 0) {
            uint t0 = (uint)f2bf(fmaxf(a0 + b1s[4*fl],     0.f))
                    | ((uint)f2bf(fmaxf(a1 + b1s[4*fl + 1], 0.f)) << 16);
            uint t1 = (uint)f2bf(fmaxf(a2 + b1s[4*fl + 2], 0.f))
                    | ((uint)f2bf(fmaxf(a3 + b1s[4*fl + 3], 0.f)) << 16);
            *(uint2*)&tsu[j * 36 + 2*fl] = make_uint2(t0, t1);
            uint t2 = (uint)f2bf(fmaxf(c0 + b1s[4*fl],     0.f))
                    | ((uint)f2bf(fmaxf(c1 + b1s[4*fl + 1], 0.f)) << 16);
            uint t3 = (uint)f2bf(fmaxf(c2 + b1s[4*fl + 2], 0.f))
                    | ((uint)f2bf(fmaxf(c3 + b1s[4*fl + 3], 0.f)) << 16);
            *(uint2*)&tsu[(j + 8) * 36 + 2*fl] = make_uint2(t2, t3);
        }
    }

    // layer2 MFMA on this wave's 16 rows (intra-wave LDS dep, in-order)
    const int m = lane & 15, quad = lane >> 4;
    floatx4 acc[2] = {(floatx4)(0.f), (floatx4)(0.f)};
    #pragma unroll
    for (int step = 0; step < 2; step++) {
        short8 a = *(const short8*)&ts[wave][m][step*32 + quad*8];
        #pragma unroll
        for (int nt = 0; nt < 2; nt++) {
            short8 bb = *(const short8*)&wf2[nt][step][lane][0];
            acc[nt] = __builtin_amdgcn_mfma_f32_16x16x32_bf16(a, bb, acc[nt], 0, 0, 0);
        }
    }
    #pragma unroll
    for (int nt = 0; nt < 2; nt++) {
        #pragma unroll
        for (int r = 0; r < 4; r++) {
            int g = b * 256 + k0 + quad*4 + r;
            if (g < N) h2[(size_t)g*32 + nt*16 + m] = f2bf(acc[nt][r]);
        }
    }
}

// ------- gather2: 16 nodes/wave, LDS edge staging + node-pair interleave,
//   8 lanes/row dwordx2, 2+2 loads per iter --------------------------------
__global__ __launch_bounds__(256, 4) void gather2_kernel(
    const u16* __restrict__ h2, const int2* __restrict__ es,
    const int2* __restrict__ off2, const float* __restrict__ b2,
    float* __restrict__ out, int N)
{
    __shared__ int2 eb[4][ECAP];
    const int tid = threadIdx.x;
    const int wave = tid >> 6, lane = tid & 63;
    const int g = lane >> 3, fl = lane & 7;           // slot 0..7, ch-group 0..7
    const int node0 = blockIdx.x * 64 + wave * 16;
    const uint2* h2v = (const uint2*)h2;   // h2 row = 8 uint2 (32 bf16, 64B)

    const int2 sg = off2[min(node0 + (lane & 15), N - 1)];
    const int beg = __builtin_amdgcn_readfirstlane(sg.x);
    const int end = __builtin_amdgcn_readlane(sg.y, 15);
    const int len = end - beg;
    const float4 bb = ((const float4*)b2)[fl];

    if (len <= ECAP) {
        for (int k = lane; k < len; k += 64) eb[wave][k] = es[beg + k];

        #pragma unroll 1
        for (int j = 0; j < 8; j++) {                 // node pair (j, j+8)
            const int pbegA = __builtin_amdgcn_readlane(sg.x, j) - beg;
            const int pendA = __builtin_amdgcn_readlane(sg.y, j) - beg;
            const int pbegB = __builtin_amdgcn_readlane(sg.x, j + 8) - beg;
            const int pendB = __builtin_amdgcn_readlane(sg.y, j + 8) - beg;
            const int clA = max(pendA - 1, 0), clB = max(pendB - 1, 0);
            float a0 = 0.f, a1 = 0.f, a2 = 0.f, a3 = 0.f;
            float c0 = 0.f, c1 = 0.f, c2 = 0.f, c3 = 0.f;
            int pA = pbegA, pB = pbegB;
            #pragma unroll 1
            while (pA < pendA || pB < pendB) {        // 16+16 edges, 4 gathers
                const int iA0 = pA + g, iA1 = pA + 8 + g;
                const int iB0 = pB + g, iB1 = pB + 8 + g;
                int2 eA0 = eb[wave][min(iA0, clA)];
                int2 eA1 = eb[wave][min(iA1, clA)];
                int2 eB0 = eb[wave][min(iB0, clB)];
                int2 eB1 = eb[wave][min(iB1, clB)];
                uint2 vA0 = h2v[(size_t)(eA0.x & 0xFFFFFF) * 8 + fl];
                uint2 vA1 = h2v[(size_t)(eA1.x & 0xFFFFFF) * 8 + fl];
                uint2 vB0 = h2v[(size_t)(eB0.x & 0xFFFFFF) * 8 + fl];
                uint2 vB1 = h2v[(size_t)(eB1.x & 0xFFFFFF) * 8 + fl];
                float wA0 = (iA0 < pendA) ? __int_as_float(eA0.y) : 0.f;
                float wA1 = (iA1 < pendA) ? __int_as_float(eA1.y) : 0.f;
                float wB0 = (iB0 < pendB) ? __int_as_float(eB0.y) : 0.f;
                float wB1 = (iB1 < pendB) ? __int_as_float(eB1.y) : 0.f;
                a0 += __uint_as_float(vA0.x << 16) * wA0 + __uint_as_float(vA1.x << 16) * wA1;
                a1 += __uint_as_float(vA0.x & 0xFFFF0000u) * wA0 + __uint_as_float(vA1.x & 0xFFFF0000u) * wA1;
                a2 += __uint_as_float(vA0.y << 16) * wA0 + __uint_as_float(vA1.y << 16) * wA1;
                a3 += __uint_as_float(vA0.y & 0xFFFF0000u) * wA0 + __uint_as_float(vA1.y & 0xFFFF0000u) * wA1;
                c0 += __uint_as_float(vB0.x << 16) * wB0 + __uint_as_float(vB1.x << 16) * wB1;
                c1 += __uint_as_float(vB0.x & 0xFFFF0000u) * wB0 + __uint_as_float(vB1.x & 0xFFFF0000u) * wB1;
                c2 += __uint_as_float(vB0.y << 16) * wB0 + __uint_as_float(vB1.y << 16) * wB1;
                c3 += __uint_as_float(vB0.y & 0xFFFF0000u) * wB0 + __uint_as_float(vB1.y & 0xFFFF0000u) * wB1;
                pA += 16; pB += 16;
            }
            a0 += __shfl_xor(a0, 8, 64);  a1 += __shfl_xor(a1, 8, 64);
            a2 += __shfl_xor(a2, 8, 64);  a3 += __shfl_xor(a3, 8, 64);
            a0 += __shfl_xor(a0, 16, 64); a1 += __shfl_xor(a1, 16, 64);
            a2 += __shfl_xor(a2, 16, 64); a3 += __shfl_xor(a3, 16, 64);
            a0 += __shfl_xor(a0, 32, 64); a1 += __shfl_xor(a1, 32, 64);
            a2 += __shfl_xor(a2, 32, 64); a3 += __shfl_xor(a3, 32, 64);
            c0 += __shfl_xor(c0, 8, 64);  c1 += __shfl_xor(c1, 8, 64);
            c2 += __shfl_xor(c2, 8, 64);  c3 += __shfl_xor(c3, 8, 64);
            c0 += __shfl_xor(c0, 16, 64); c1 += __shfl_xor(c1, 16, 64);
            c2 += __shfl_xor(c2, 16, 64); c3 += __shfl_xor(c3, 16, 64);
            c0 += __shfl_xor(c0, 32, 64); c1 += __shfl_xor(c1, 32, 64);
            c2 += __shfl_xor(c2, 32, 64); c3 += __shfl_xor(c3, 32, 64);
            const int dA = node0 + j, dB = node0 + j + 8;
            if (g == 0 && dA < N)
                *(float4*)&out[(size_t)dA * 32 + 4 * fl] =
                    make_float4(a0 + bb.x, a1 + bb.y, a2 + bb.z, a3 + bb.w);
            if (g == 0 && dB < N)
                *(float4*)&out[(size_t)dB * 32 + 4 * fl] =
                    make_float4(c0 + bb.x, c1 + bb.y, c2 + bb.z, c3 + bb.w);
        }
    } else {
        #pragma unroll 1
        for (int i = 0; i < 16; i++) {
            const int pbeg = __builtin_amdgcn_readlane(sg.x, i);
            const int pend = __builtin_amdgcn_readlane(sg.y, i);
            const int cl = max(pend - 1, 0);
            float a0 = 0.f, a1 = 0.f, a2 = 0.f, a3 = 0.f;
            #pragma unroll 1
            for (int p = pbeg; p < pend; p += 32) {
                const int i0 = p + g, i1 = p + 8 + g, i2 = p + 16 + g, i3 = p + 24 + g;
                int2 e0 = es[min(i0, cl)];
                int2 e1 = es[min(i1, cl)];
                int2 e2 = es[min(i2, cl)];
                int2 e3 = es[min(i3, cl)];
                uint2 v0 = h2v[(size_t)(e0.x & 0xFFFFFF) * 8 + fl];
                uint2 v1 = h2v[(size_t)(e1.x & 0xFFFFFF) * 8 + fl];
                uint2 v2 = h2v[(size_t)(e2.x & 0xFFFFFF) * 8 + fl];
                uint2 v3 = h2v[(size_t)(e3.x & 0xFFFFFF) * 8 + fl];
                float w0 = (i0 < pend) ? __int_as_float(e0.y) : 0.f;
                float w1 = (i1 < pend) ? __int_as_float(e1.y) : 0.f;
                float w2 = (i2 < pend) ? __int_as_float(e2.y) : 0.f;
                float w3 = (i3 < pend) ? __int_as_float(e3.y) : 0.f;
                a0 += __uint_as_float(v0.x << 16) * w0 + __uint_as_float(v1.x << 16) * w1
                    + __uint_as_float(v2.x << 16) * w2 + __uint_as_float(v3.x << 16) * w3;
                a1 += __uint_as_float(v0.x & 0xFFFF0000u) * w0 + __uint_as_float(v1.x & 0xFFFF0000u) * w1
                    + __uint_as_float(v2.x & 0xFFFF0000u) * w2 + __uint_as_float(v3.x & 0xFFFF0000u) * w3;
                a2 += __uint_as_float(v0.y << 16) * w0 + __uint_as_float(v1.y << 16) * w1
                    + __uint_as_float(v2.y << 16) * w2 + __uint_as_float(v3.y << 16) * w3;
                a3 += __uint_as_float(v0.y & 0xFFFF0000u) * w0 + __uint_as_float(v1.y & 0xFFFF0000u) * w1
                    + __uint_as_float(v2.y & 0xFFFF0000u) * w2 + __uint_as_float(v3.y & 0xFFFF0000u) * w3;
            }
            a0 += __shfl_xor(a0, 8, 64);  a1 += __shfl_xor(a1, 8, 64);
            a2 += __shfl_xor(a2, 8, 64);  a3 += __shfl_xor(a3, 8, 64);
            a0 += __shfl_xor(a0, 16, 64); a1 += __shfl_xor(a1, 16, 64);
            a2 += __shfl_xor(a2, 16, 64); a3 += __shfl_xor(a3, 16, 64);
            a0 += __shfl_xor(a0, 32, 64); a1 += __shfl_xor(a1, 32, 64);
            a2 += __shfl_xor(a2, 32, 64); a3 += __shfl_xor(a3, 32, 64);
            const int d = node0 + i;
            if (g == 0 && d < N)
                *(float4*)&out[(size_t)d * 32 + 4 * fl] =
                    make_float4(a0 + bb.x, a1 + bb.y, a2 + bb.z, a3 + bb.w);
        }
    }
}

extern "C" void kernel_launch(void* const* d_in, const int* in_sizes, int n_in,
                              void* d_out, int out_size, void* d_ws, size_t ws_size,
                              hipStream_t stream)
{
    const float* x   = (const float*)d_in[0];
    const int*  esrc = (const int*)d_in[1];
    const int*  edst = (const int*)d_in[2];
    const float* ew  = (const float*)d_in[3];
    const float* W1  = (const float*)d_in[4];
    const float* b1  = (const float*)d_in[5];
    const float* W2  = (const float*)d_in[6];
    const float* b2  = (const float*)d_in[7];
    float* out = (float*)d_out;

    const int N = in_sizes[0] / 128;   // 100000
    const int E = in_sizes[1];         // 1600000
    const int nb = (N + 255) >> 8;     // 391 buckets

    // slack bucket capacity: mean + ~8 sigma, 16-aligned (= CAPC for these shapes)
    const int mean = (E + nb - 1) / nb;
    int s = 1; while (s * s < mean) s++;                  // ceil sqrt
    int cap = (mean + 8 * s + 15) & ~15;                  // 4608
    if (cap > CAPC) cap = CAPC;

    char* base = (char*)d_ws;
    size_t o = 0;
    auto alloc = [&](size_t bytes) { char* p = base + o; o = (o + bytes + 255) & ~(size_t)255; return p; };
    u16*  h1      = (u16*) alloc((size_t)N * 64 * 2);
    u16*  h2      = (u16*) alloc((size_t)N * 32 * 2);
    int2* es      = (int2*)alloc((size_t)nb * cap * 8);
    int2* es2     = (int2*)alloc((size_t)nb * cap * 8);
    int2* off2    = (int2*)alloc((size_t)N * 8);
    int*  gcursor = (int*) alloc(512 * 4);
    u16*  wfg     = (u16*) alloc(8192 * 2);               // W1 frags, 16 KB

    const int pblocks = (E + CHUNK - 1) / CHUNK;   // 782 partition blocks
    const int gblocks = (N + 63) / 64;             // 1563 gemm blocks

    init_kernel<<<8, 256, 0, stream>>>(W1, wfg, gcursor);
    g1p_kernel<<<pblocks + gblocks, 256, 0, stream>>>(
        x, wfg, h1, N, esrc, edst, ew, gcursor, es, E, cap, pblocks);
    sg1_kernel<<<2 * nb, 512, 0, stream>>>(h1, es, gcursor, es2, off2, b1, W2, h2, N, cap);
    gather2_kernel<<<(N + 63) / 64, 256, 0, stream>>>(h2, es2, off2, b2, out, N);
}

// Round 10
// 216.015 us; speedup vs baseline: 1.0535x; 1.0000x over previous
//
#include <hip/hip_runtime.h>
#include <hip/hip_bf16.h>

// GCN 2-layer, slack-bucket dst-radix-sort + batched wave gathers:
//   init: zero gcursor + pre-swizzle W1 -> bf16 fragment order (wfg)
//   fused dispatch: blocks [0,pblocks) partition edges into slack bucket
//     regions (hist -> scan -> LDS group -> coalesced run writes);
//     blocks [pblocks,..) are PERSISTENT GEMM blocks: W1 frags staged once,
//     then grid-stride over 64-row tiles {stage x, sync, MFMA, store, sync}
//   sg1 (FUSED sort+gather1, SPLIT): TWO blocks per bucket (512 thr).
//     Each hists the full bucket, sorts only its node-half (keys 0-127 /
//     128-255) into LDS, writes its es2 half + off2 (h==0); then 8 waves
//     x 16 nodes gather h1 from LDS-sorted edges (node-pair interleave,
//     16 lanes/row dwordx2); layer2 (relu(+b1) @ W2) via MFMA -> h2
//   gather2 (LDS edge staging + node-pair interleave): 8 lanes/row dwordx2

typedef unsigned short u16;
typedef unsigned int uint;
typedef short short8 __attribute__((ext_vector_type(8)));
typedef float floatx4 __attribute__((ext_vector_type(4)));

static __device__ __forceinline__ u16 f2bf(float f) {
    unsigned int u = __float_as_uint(f);
    return (u16)((u + 0x7fff + ((u >> 16) & 1)) >> 16);   // RNE
}

#define F4C(v, j) ((j)==0?(v).x:((j)==1?(v).y:((j)==2?(v).z:(v).w)))
#define CHUNK 2048
#define CAPC 4608   // bucket capacity (mean 4096 + 8 sigma, 16-aligned) = host cap
#define SCAPH 2816  // node-half LDS capacity (mean 2048, +24 sigma)
#define ECAP 384    // gather2 per-wave LDS edge-buffer capacity
#define GBLK 1024   // persistent GEMM blocks

// ------- init: zero gcursor + W1 (128x64 f32) -> bf16 B-fragment order -----
__global__ __launch_bounds__(256) void init_kernel(
    const float* __restrict__ W1, u16* __restrict__ wfg, int* __restrict__ gcursor)
{
    const int idx = blockIdx.x * 256 + threadIdx.x;       // grid 8x256 = 2048
    if (idx < 512) gcursor[idx] = 0;
    const float4 v = ((const float4*)W1)[idx];
    const int k = idx >> 4, n4 = (idx & 15) * 4;
    const int step = k >> 5, klane = (k >> 3) & 3, j = k & 7;
    #pragma unroll
    for (int c = 0; c < 4; c++) {
        int n = n4 + c;
        wfg[(((n >> 4) * 4 + step) * 64 + klane * 16 + (n & 15)) * 8 + j] = f2bf(F4C(v, c));
    }
}

// ------- fused: partition (blocks 0..pblocks-1) + GEMM h1=x@W1 (rest) -------
// edge entry: x = src | (dst&255)<<24 ; y = w bits
union __align__(16) SharedU {
    struct {                                   // GEMM part (33.8 KB)
        u16 xs[64][136];
        u16 wf[4][4][64][8];                   // [ntile][step][lane][j]
    } g;
    struct {                                   // partition part (30.7 KB)
        int2 stage[CHUNK];                     // 16 KB
        u16  stb[CHUNK];                       // 4 KB
        int  hist[512], sc[512], xscan[512], place[512], runbase[512];
    } p;
};

__global__ __launch_bounds__(256, 4) void g1p_kernel(
    const float* __restrict__ x, const u16* __restrict__ wfg,
    u16* __restrict__ h1, int N,
    const int* __restrict__ src, const int* __restrict__ dst,
    const float* __restrict__ w, int* __restrict__ gcursor,
    int2* __restrict__ es, int E, int cap, int pblocks)
{
    __shared__ SharedU sh;
    const int tid = threadIdx.x;

    if (blockIdx.x < pblocks) {            // ---------- partition ----------
        const int base = blockIdx.x * CHUNK;
        const int nloc = min(CHUNK, E - base);

        sh.p.hist[tid] = 0; sh.p.hist[tid + 256] = 0;
        __syncthreads();
        for (int i = tid; i < nloc; i += 256)
            atomicAdd(&sh.p.hist[dst[base + i] >> 8], 1);
        __syncthreads();

        sh.p.sc[tid] = sh.p.hist[tid];
        sh.p.sc[tid + 256] = sh.p.hist[tid + 256];
        __syncthreads();
        for (int o = 1; o < 512; o <<= 1) {          // inclusive scan, 512 wide
            int v0 = (tid >= o) ? sh.p.sc[tid - o] : 0;
            int v1 = (tid + 256 >= o) ? sh.p.sc[tid + 256 - o] : 0;
            __syncthreads();
            sh.p.sc[tid] += v0;
            sh.p.sc[tid + 256] += v1;
            __syncthreads();
        }
        sh.p.xscan[tid] = sh.p.sc[tid] - sh.p.hist[tid];
        sh.p.xscan[tid + 256] = sh.p.sc[tid + 256] - sh.p.hist[tid + 256];
        sh.p.place[tid] = sh.p.xscan[tid];
        sh.p.place[tid + 256] = sh.p.xscan[tid + 256];
        __syncthreads();

        for (int i = tid; i < nloc; i += 256) {      // group by bucket in LDS
            int d = dst[base + i];
            int b = d >> 8;
            int pos = atomicAdd(&sh.p.place[b], 1);
            sh.p.stage[pos] = make_int2(src[base + i] | ((d & 255) << 24),
                                        __float_as_int(w[base + i]));
            sh.p.stb[pos] = (u16)b;
        }
        __syncthreads();

        {   // reserve runs in slack regions
            int l0 = sh.p.hist[tid], l1 = sh.p.hist[tid + 256];
            sh.p.runbase[tid]       = l0 ? atomicAdd(&gcursor[tid], l0)       : 0;
            sh.p.runbase[tid + 256] = l1 ? atomicAdd(&gcursor[tid + 256], l1) : 0;
        }
        __syncthreads();

        for (int i = tid; i < nloc; i += 256) {      // contiguous run writes
            int b = sh.p.stb[i];
            es[(size_t)b * cap + sh.p.runbase[b] + (i - sh.p.xscan[b])] = sh.p.stage[i];
        }
        return;
    }

    // ---------- GEMM (persistent: W1 staged once, grid-stride tiles) -------
    {   // copy pre-swizzled W1 fragments (16 KB), conflict-free
        const float4* wg4 = (const float4*)wfg;
        float4* wl4 = (float4*)&sh.g.wf[0][0][0][0];
        #pragma unroll
        for (int i = 0; i < 4; i++) wl4[tid + i*256] = wg4[tid + i*256];
    }

    const int wave = tid >> 6, lane = tid & 63;
    const int m = lane & 15, quad = lane >> 4;
    const int rw = wave * 16;
    const int ntiles = (N + 63) >> 6;
    const float4* x4 = (const float4*)x;

    for (int tile = blockIdx.x - pblocks; tile < ntiles; tile += GBLK) {
        const int row0 = tile * 64;
        {   // stage x tile -> bf16
            #pragma unroll
            for (int i = 0; i < 8; i++) {
                int idx = tid + i*256;
                int r = idx >> 5, kc = idx & 31;
                int gr = row0 + r;
                float4 v = make_float4(0.f,0.f,0.f,0.f);
                if (gr < N) v = x4[gr*32 + kc];
                ushort4 o;
                o.x = f2bf(v.x); o.y = f2bf(v.y); o.z = f2bf(v.z); o.w = f2bf(v.w);
                *(ushort4*)&sh.g.xs[r][kc*4] = o;
            }
        }
        __syncthreads();

        floatx4 acc[4] = {(floatx4)(0.f), (floatx4)(0.f), (floatx4)(0.f), (floatx4)(0.f)};
        #pragma unroll
        for (int step = 0; step < 4; step++) {
            short8 a = *(const short8*)&sh.g.xs[rw + m][step*32 + quad*8];
            #pragma unroll
            for (int nt = 0; nt < 4; nt++) {
                short8 b = *(const short8*)&sh.g.wf[nt][step][lane][0];
                acc[nt] = __builtin_amdgcn_mfma_f32_16x16x32_bf16(a, b, acc[nt], 0, 0, 0);
            }
        }
        #pragma unroll
        for (int nt = 0; nt < 4; nt++) {
            #pragma unroll
            for (int r = 0; r < 4; r++) {
                int gr = row0 + rw + quad*4 + r;
                if (gr < N) h1[(size_t)gr*64 + nt*16 + m] = f2bf(acc[nt][r]);
            }
        }
        __syncthreads();   // xs reads done before next tile's stage overwrites
    }
}

// ------- sg1 (split): 2 blocks/bucket. Full-bucket hist+scan; sort own
//   node-half into LDS; es2/off2 writeback; gather+layer2 for 128 nodes ----
__global__ __launch_bounds__(512, 6) void sg1_kernel(
    const u16* __restrict__ h1, const int2* __restrict__ es,
    const int* __restrict__ gcursor, int2* __restrict__ es2,
    int2* __restrict__ off2, const float* __restrict__ b1,
    const float* __restrict__ W2, u16* __restrict__ h2, int N, int cap)
{
    __shared__ int2 sortedH[SCAPH];                   // 22.5 KB node-half edges
    __shared__ __align__(16) u16 ts[8][16][72];       // 18.4 KB (per-wave rows)
    __shared__ __align__(16) u16 wf2[2][2][64][8];    // [ntile][step][lane][j]
    __shared__ float b1s[64];
    __shared__ int hist[256], exs[256], cur[256];
    const int t = threadIdx.x;
    const int b = blockIdx.x >> 1, hh = blockIdx.x & 1;
    const int e0 = b * cap;
    const int len = min(gcursor[b], cap);

    {   // stage W2 (512 float4, one per thread) -> bf16 B-fragments, + b1
        const float4* s4 = (const float4*)W2;
        float4 v = s4[t];
        int k = t >> 3, n4 = (t & 7) * 4;
        int step = k >> 5, quad = (k >> 3) & 3, j = k & 7;
        #pragma unroll
        for (int c = 0; c < 4; c++) {
            int n = n4 + c;
            wf2[n >> 4][step][quad*16 + (n & 15)][j] = f2bf(F4C(v, c));
        }
        if (t < 16) ((float4*)b1s)[t] = ((const float4*)b1)[t];
        if (t < 256) hist[t] = 0;
    }
    __syncthreads();

    // ---- phase 1: full bucket -> regs, hist by low byte ----
    int2 re[9]; int rk[9];
    #pragma unroll
    for (int k = 0; k < 9; k++) {
        int i = t + k * 512;
        if (i < len) {
            re[k] = es[e0 + i];
            rk[k] = (int)(((unsigned)re[k].x) >> 24);
            atomicAdd(&hist[rk[k]], 1);
        } else rk[k] = -1;
    }
    __syncthreads();

    int v = 0;
    if (t < 256) { v = hist[t]; cur[t] = v; }         // cur as scan buffer
    __syncthreads();
    for (int o = 1; o < 256; o <<= 1) {
        int add = 0;
        if (t < 256 && t >= o) add = cur[t - o];
        __syncthreads();
        if (t < 256) cur[t] += add;
        __syncthreads();
    }
    if (t < 256) {
        int ex = cur[t] - v;                          // exclusive scan
        exs[t] = ex;
        if (hh == 0) {
            int g = b * 256 + t;
            if (g < N) off2[g] = make_int2(e0 + ex, e0 + ex + v);
        }
    }
    __syncthreads();

    const int baseH = hh ? exs[128] : 0;
    const int halflen = hh ? (len - exs[128]) : exs[128];
    if (t < 256) cur[t] = exs[t] - baseH;             // scatter cursor (own half)
    __syncthreads();

    #pragma unroll
    for (int k = 0; k < 9; k++)                       // scatter own half -> LDS
        if (rk[k] >= 0 && (rk[k] >> 7) == hh) {
            int pos = atomicAdd(&cur[rk[k]], 1);
            sortedH[min(pos, SCAPH - 1)] = re[k];
        }
    __syncthreads();

    for (int i = t; i < halflen; i += 512)            // coalesced es2 writeback
        es2[e0 + baseH + i] = sortedH[i];

    // ---- phase 2: gather h1; 8 waves x 16 nodes (keys hh*128 + w*16 + j) ----
    const int wave = t >> 6, lane = t & 63;
    const int h = lane >> 4, fl = lane & 15;          // slot 0..3, ch-group 0..15
    const uint2* h1v = (const uint2*)h1;   // h1 row = 16 uint2 (64 bf16, 128B)
    uint* tsu = (uint*)&ts[wave][0][0];    // this wave's 16 rows of 36 uints
    const int k0 = hh * 128 + wave * 16;              // first key of this wave

    #pragma unroll 1
    for (int j = 0; j < 8; j++) {                     // node pair (j, j+8)
        const int nA = k0 + j, nB = k0 + j + 8;
        const int pbegA = exs[nA] - baseH, pendA = pbegA + hist[nA];
        const int pbegB = exs[nB] - baseH, pendB = pbegB + hist[nB];
        const int clA = max(pendA - 1, 0), clB = max(pendB - 1, 0);
        float a0 = 0.f, a1 = 0.f, a2 = 0.f, a3 = 0.f;
        float c0 = 0.f, c1 = 0.f, c2 = 0.f, c3 = 0.f;
        int pA = pbegA, pB = pbegB;
        #pragma unroll 1
        while (pA < pendA || pB < pendB) {            // 16+16 edges, 8 gathers
            const int iA0 = pA + h,     iA1 = pA + 4 + h;
            const int iA2 = pA + 8 + h, iA3 = pA + 12 + h;
            const int iB0 = pB + h,     iB1 = pB + 4 + h;
            const int iB2 = pB + 8 + h, iB3 = pB + 12 + h;
            int2 eA0 = sortedH[min(iA0, clA)];
            int2 eA1 = sortedH[min(iA1, clA)];
            int2 eA2 = sortedH[min(iA2, clA)];
            int2 eA3 = sortedH[min(iA3, clA)];
            int2 eB0 = sortedH[min(iB0, clB)];
            int2 eB1 = sortedH[min(iB1, clB)];
            int2 eB2 = sortedH[min(iB2, clB)];
            int2 eB3 = sortedH[min(iB3, clB)];
            uint2 vA0 = h1v[(size_t)(eA0.x & 0xFFFFFF) * 16 + fl];
            uint2 vA1 = h1v[(size_t)(eA1.x & 0xFFFFFF) * 16 + fl];
            uint2 vA2 = h1v[(size_t)(eA2.x & 0xFFFFFF) * 16 + fl];
            uint2 vA3 = h1v[(size_t)(eA3.x & 0xFFFFFF) * 16 + fl];
            uint2 vB0 = h1v[(size_t)(eB0.x & 0xFFFFFF) * 16 + fl];
            uint2 vB1 = h1v[(size_t)(eB1.x & 0xFFFFFF) * 16 + fl];
            uint2 vB2 = h1v[(size_t)(eB2.x & 0xFFFFFF) * 16 + fl];
            uint2 vB3 = h1v[(size_t)(eB3.x & 0xFFFFFF) * 16 + fl];
            float wA0 = (iA0 < pendA) ? __int_as_float(eA0.y) : 0.f;
            float wA1 = (iA1 < pendA) ? __int_as_float(eA1.y) : 0.f;
            float wA2 = (iA2 < pendA) ? __int_as_float(eA2.y) : 0.f;
            float wA3 = (iA3 < pendA) ? __int_as_float(eA3.y) : 0.f;
            float wB0 = (iB0 < pendB) ? __int_as_float(eB0.y) : 0.f;
            float wB1 = (iB1 < pendB) ? __int_as_float(eB1.y) : 0.f;
            float wB2 = (iB2 < pendB) ? __int_as_float(eB2.y) : 0.f;
            float wB3 = (iB3 < pendB) ? __int_as_float(eB3.y) : 0.f;
            a0 += __uint_as_float(vA0.x << 16) * wA0 + __uint_as_float(vA1.x << 16) * wA1
                + __uint_as_float(vA2.x << 16) * wA2 + __uint_as_float(vA3.x << 16) * wA3;
            a1 += __uint_as_float(vA0.x & 0xFFFF0000u) * wA0 + __uint_as_float(vA1.x & 0xFFFF0000u) * wA1
                + __uint_as_float(vA2.x & 0xFFFF0000u) * wA2 + __uint_as_float(vA3.x & 0xFFFF0000u) * wA3;
            a2 += __uint_as_float(vA0.y << 16) * wA0 + __uint_as_float(vA1.y << 16) * wA1
                + __uint_as_float(vA2.y << 16) * wA2 + __uint_as_float(vA3.y << 16) * wA3;
            a3 += __uint_as_float(vA0.y & 0xFFFF0000u) * wA0 + __uint_as_float(vA1.y & 0xFFFF0000u) * wA1
                + __uint_as_float(vA2.y & 0xFFFF0000u) * wA2 + __uint_as_float(vA3.y & 0xFFFF0000u) * wA3;
            c0 += __uint_as_float(vB0.x << 16) * wB0 + __uint_as_float(vB1.x << 16) * wB1
                + __uint_as_float(vB2.x << 16) * wB2 + __uint_as_float(vB3.x << 16) * wB3;
            c1 += __uint_as_float(vB0.x & 0xFFFF0000u) * wB0 + __uint_as_float(vB1.x & 0xFFFF0000u) * wB1
                + __uint_as_float(vB2.x & 0xFFFF0000u) * wB2 + __uint_as_float(vB3.x & 0xFFFF0000u) * wB3;
            c2 += __uint_as_float(vB0.y << 16) * wB0 + __uint_as_float(vB1.y << 16) * wB1
                + __uint_as_float(vB2.y << 16) * wB2 + __uint_as_float(vB3.y << 16) * wB3;
            c3 += __uint_as_float(vB0.y & 0xFFFF0000u) * wB0 + __uint_as_float(vB1.y & 0xFFFF0000u) * wB1
                + __uint_as_float(vB2.y & 0xFFFF0000u) * wB2 + __uint_as_float(vB3.y & 0xFFFF0000u) * wB3;
            pA += 16; pB += 16;
        }
        a0 += __shfl_xor(a0, 16, 64); a1 += __shfl_xor(a1, 16, 64);
        a2 += __shfl_xor(a2, 16, 64); a3 += __shfl_xor(a3, 16, 64);
        a0 += __shfl_xor(a0, 32, 64); a1 += __shfl_xor(a1, 32, 64);
        a2 += __shfl_xor(a2, 32, 64); a3 += __shfl_xor(a3, 32, 64);
        c0 += __shfl_xor(c0, 16, 64); c1 += __shfl_xor(c1, 16, 64);
        c2 += __shfl_xor(c2, 16, 64); c3 += __shfl_xor(c3, 16, 64);
        c0 += __shfl_xor(c0, 32, 64); c1 += __shfl_xor(c1, 32, 64);
        c2 += __shfl_xor(c2, 32, 64); c3 += __shfl_xor(c3, 32, 64);
        if (h == 0) {
            uint t0 = (uint)f2bf(fmaxf(a0 + b1s[4*fl],     0.f))
                    | ((uint)f2bf(fmaxf(a1 + b1s[4*fl + 1], 0.f)) << 16);
            uint t1 = (uint)f2bf(fmaxf(a2 + b1s[4*fl + 2], 0.f))
                    | ((uint)f2bf(fmaxf(a3 + b1s[4*fl + 3], 0.f)) << 16);
            *(uint2*)&tsu[j * 36 + 2*fl] = make_uint2(t0, t1);
            uint t2 = (uint)f2bf(fmaxf(c0 + b1s[4*fl],     0.f))
                    | ((uint)f2bf(fmaxf(c1 + b1s[4*fl + 1], 0.f)) << 16);
            uint t3 = (uint)f2bf(fmaxf(c2 + b1s[4*fl + 2], 0.f))
                    | ((uint)f2bf(fmaxf(c3 + b1s[4*fl + 3], 0.f)) << 16);
            *(uint2*)&tsu[(j + 8) * 36 + 2*fl] = make_uint2(t2, t3);
        }
    }

    // layer2 MFMA on this wave's 16 rows (intra-wave LDS dep, in-order)
    const int m = lane & 15, quad = lane >> 4;
    floatx4 acc[2] = {(floatx4)(0.f), (floatx4)(0.f)};
    #pragma unroll
    for (int step = 0; step < 2; step++) {
        short8 a = *(const short8*)&ts[wave][m][step*32 + quad*8];
        #pragma unroll
        for (int nt = 0; nt < 2; nt++) {
            short8 bb = *(const short8*)&wf2[nt][step][lane][0];
            acc[nt] = __builtin_amdgcn_mfma_f32_16x16x32_bf16(a, bb, acc[nt], 0, 0, 0);
        }
    }
    #pragma unroll
    for (int nt = 0; nt < 2; nt++) {
        #pragma unroll
        for (int r = 0; r < 4; r++) {
            int g = b * 256 + k0 + quad*4 + r;
            if (g < N) h2[(size_t)g*32 + nt*16 + m] = f2bf(acc[nt][r]);
        }
    }
}

// ------- gather2: 16 nodes/wave, LDS edge staging + node-pair interleave,
//   8 lanes/row dwordx2, 2+2 loads per iter --------------------------------
__global__ __launch_bounds__(256, 4) void gather2_kernel(
    const u16* __restrict__ h2, const int2* __restrict__ es,
    const int2* __restrict__ off2, const float* __restrict__ b2,
    float* __restrict__ out, int N)
{
    __shared__ int2 eb[4][ECAP];
    const int tid = threadIdx.x;
    const int wave = tid >> 6, lane = tid & 63;
    const int g = lane >> 3, fl = lane & 7;           // slot 0..7, ch-group 0..7
    const int node0 = blockIdx.x * 64 + wave * 16;
    const uint2* h2v = (const uint2*)h2;   // h2 row = 8 uint2 (32 bf16, 64B)

    const int2 sg = off2[min(node0 + (lane & 15), N - 1)];
    const int beg = __builtin_amdgcn_readfirstlane(sg.x);
    const int end = __builtin_amdgcn_readlane(sg.y, 15);
    const int len = end - beg;
    const float4 bb = ((const float4*)b2)[fl];

    if (len <= ECAP) {
        for (int k = lane; k < len; k += 64) eb[wave][k] = es[beg + k];

        #pragma unroll 1
        for (int j = 0; j < 8; j++) {                 // node pair (j, j+8)
            const int pbegA = __builtin_amdgcn_readlane(sg.x, j) - beg;
            const int pendA = __builtin_amdgcn_readlane(sg.y, j) - beg;
            const int pbegB = __builtin_amdgcn_readlane(sg.x, j + 8) - beg;
            const int pendB = __builtin_amdgcn_readlane(sg.y, j + 8) - beg;
            const int clA = max(pendA - 1, 0), clB = max(pendB - 1, 0);
            float a0 = 0.f, a1 = 0.f, a2 = 0.f, a3 = 0.f;
            float c0 = 0.f, c1 = 0.f, c2 = 0.f, c3 = 0.f;
            int pA = pbegA, pB = pbegB;
            #pragma unroll 1
            while (pA < pendA || pB < pendB) {        // 16+16 edges, 4 gathers
                const int iA0 = pA + g, iA1 = pA + 8 + g;
                const int iB0 = pB + g, iB1 = pB + 8 + g;
                int2 eA0 = eb[wave][min(iA0, clA)];
                int2 eA1 = eb[wave][min(iA1, clA)];
                int2 eB0 = eb[wave][min(iB0, clB)];
                int2 eB1 = eb[wave][min(iB1, clB)];
                uint2 vA0 = h2v[(size_t)(eA0.x & 0xFFFFFF) * 8 + fl];
                uint2 vA1 = h2v[(size_t)(eA1.x & 0xFFFFFF) * 8 + fl];
                uint2 vB0 = h2v[(size_t)(eB0.x & 0xFFFFFF) * 8 + fl];
                uint2 vB1 = h2v[(size_t)(eB1.x & 0xFFFFFF) * 8 + fl];
                float wA0 = (iA0 < pendA) ? __int_as_float(eA0.y) : 0.f;
                float wA1 = (iA1 < pendA) ? __int_as_float(eA1.y) : 0.f;
                float wB0 = (iB0 < pendB) ? __int_as_float(eB0.y) : 0.f;
                float wB1 = (iB1 < pendB) ? __int_as_float(eB1.y) : 0.f;
                a0 += __uint_as_float(vA0.x << 16) * wA0 + __uint_as_float(vA1.x << 16) * wA1;
                a1 += __uint_as_float(vA0.x & 0xFFFF0000u) * wA0 + __uint_as_float(vA1.x & 0xFFFF0000u) * wA1;
                a2 += __uint_as_float(vA0.y << 16) * wA0 + __uint_as_float(vA1.y << 16) * wA1;
                a3 += __uint_as_float(vA0.y & 0xFFFF0000u) * wA0 + __uint_as_float(vA1.y & 0xFFFF0000u) * wA1;
                c0 += __uint_as_float(vB0.x << 16) * wB0 + __uint_as_float(vB1.x << 16) * wB1;
                c1 += __uint_as_float(vB0.x & 0xFFFF0000u) * wB0 + __uint_as_float(vB1.x & 0xFFFF0000u) * wB1;
                c2 += __uint_as_float(vB0.y << 16) * wB0 + __uint_as_float(vB1.y << 16) * wB1;
                c3 += __uint_as_float(vB0.y & 0xFFFF0000u) * wB0 + __uint_as_float(vB1.y & 0xFFFF0000u) * wB1;
                pA += 16; pB += 16;
            }
            a0 += __shfl_xor(a0, 8, 64);  a1 += __shfl_xor(a1, 8, 64);
            a2 += __shfl_xor(a2, 8, 64);  a3 += __shfl_xor(a3, 8, 64);
            a0 += __shfl_xor(a0, 16, 64); a1 += __shfl_xor(a1, 16, 64);
            a2 += __shfl_xor(a2, 16, 64); a3 += __shfl_xor(a3, 16, 64);
            a0 += __shfl_xor(a0, 32, 64); a1 += __shfl_xor(a1, 32, 64);
            a2 += __shfl_xor(a2, 32, 64); a3 += __shfl_xor(a3, 32, 64);
            c0 += __shfl_xor(c0, 8, 64);  c1 += __shfl_xor(c1, 8, 64);
            c2 += __shfl_xor(c2, 8, 64);  c3 += __shfl_xor(c3, 8, 64);
            c0 += __shfl_xor(c0, 16, 64); c1 += __shfl_xor(c1, 16, 64);
            c2 += __shfl_xor(c2, 16, 64); c3 += __shfl_xor(c3, 16, 64);
            c0 += __shfl_xor(c0, 32, 64); c1 += __shfl_xor(c1, 32, 64);
            c2 += __shfl_xor(c2, 32, 64); c3 += __shfl_xor(c3, 32, 64);
            const int dA = node0 + j, dB = node0 + j + 8;
            if (g == 0 && dA < N)
                *(float4*)&out[(size_t)dA * 32 + 4 * fl] =
                    make_float4(a0 + bb.x, a1 + bb.y, a2 + bb.z, a3 + bb.w);
            if (g == 0 && dB < N)
                *(float4*)&out[(size_t)dB * 32 + 4 * fl] =
                    make_float4(c0 + bb.x, c1 + bb.y, c2 + bb.z, c3 + bb.w);
        }
    } else {
        #pragma unroll 1
        for (int i = 0; i < 16; i++) {
            const int pbeg = __builtin_amdgcn_readlane(sg.x, i);
            const int pend = __builtin_amdgcn_readlane(sg.y, i);
            const int cl = max(pend - 1, 0);
            float a0 = 0.f, a1 = 0.f, a2 = 0.f, a3 = 0.f;
            #pragma unroll 1
            for (int p = pbeg; p < pend; p += 32) {
                const int i0 = p + g, i1 = p + 8 + g, i2 = p + 16 + g, i3 = p + 24 + g;
                int2 e0 = es[min(i0, cl)];
                int2 e1 = es[min(i1, cl)];
                int2 e2 = es[min(i2, cl)];
                int2 e3 = es[min(i3, cl)];
                uint2 v0 = h2v[(size_t)(e0.x & 0xFFFFFF) * 8 + fl];
                uint2 v1 = h2v[(size_t)(e1.x & 0xFFFFFF) * 8 + fl];
                uint2 v2 = h2v[(size_t)(e2.x & 0xFFFFFF) * 8 + fl];
                uint2 v3 = h2v[(size_t)(e3.x & 0xFFFFFF) * 8 + fl];
                float w0 = (i0 < pend) ? __int_as_float(e0.y) : 0.f;
                float w1 = (i1 < pend) ? __int_as_float(e1.y) : 0.f;
                float w2 = (i2 < pend) ? __int_as_float(e2.y) : 0.f;
                float w3 = (i3 < pend) ? __int_as_float(e3.y) : 0.f;
                a0 += __uint_as_float(v0.x << 16) * w0 + __uint_as_float(v1.x << 16) * w1
                    + __uint_as_float(v2.x << 16) * w2 + __uint_as_float(v3.x << 16) * w3;
                a1 += __uint_as_float(v0.x & 0xFFFF0000u) * w0 + __uint_as_float(v1.x & 0xFFFF0000u) * w1
                    + __uint_as_float(v2.x & 0xFFFF0000u) * w2 + __uint_as_float(v3.x & 0xFFFF0000u) * w3;
                a2 += __uint_as_float(v0.y << 16) * w0 + __uint_as_float(v1.y << 16) * w1
                    + __uint_as_float(v2.y << 16) * w2 + __uint_as_float(v3.y << 16) * w3;
                a3 += __uint_as_float(v0.y & 0xFFFF0000u) * w0 + __uint_as_float(v1.y & 0xFFFF0000u) * w1
                    + __uint_as_float(v2.y & 0xFFFF0000u) * w2 + __uint_as_float(v3.y & 0xFFFF0000u) * w3;
            }
            a0 += __shfl_xor(a0, 8, 64);  a1 += __shfl_xor(a1, 8, 64);
            a2 += __shfl_xor(a2, 8, 64);  a3 += __shfl_xor(a3, 8, 64);
            a0 += __shfl_xor(a0, 16, 64); a1 += __shfl_xor(a1, 16, 64);
            a2 += __shfl_xor(a2, 16, 64); a3 += __shfl_xor(a3, 16, 64);
            a0 += __shfl_xor(a0, 32, 64); a1 += __shfl_xor(a1, 32, 64);
            a2 += __shfl_xor(a2, 32, 64); a3 += __shfl_xor(a3, 32, 64);
            const int d = node0 + i;
            if (g == 0 && d < N)
                *(float4*)&out[(size_t)d * 32 + 4 * fl] =
                    make_float4(a0 + bb.x, a1 + bb.y, a2 + bb.z, a3 + bb.w);
        }
    }
}

extern "C" void kernel_launch(void* const* d_in, const int* in_sizes, int n_in,
                              void* d_out, int out_size, void* d_ws, size_t ws_size,
                              hipStream_t stream)
{
    const float* x   = (const float*)d_in[0];
    const int*  esrc = (const int*)d_in[1];
    const int*  edst = (const int*)d_in[2];
    const float* ew  = (const float*)d_in[3];
    const float* W1  = (const float*)d_in[4];
    const float* b1  = (const float*)d_in[5];
    const float* W2  = (const float*)d_in[6];
    const float* b2  = (const float*)d_in[7];
    float* out = (float*)d_out;

    const int N = in_sizes[0] / 128;   // 100000
    const int E = in_sizes[1];         // 1600000
    const int nb = (N + 255) >> 8;     // 391 buckets

    // slack bucket capacity: mean + ~8 sigma, 16-aligned (= CAPC for these shapes)
    const int mean = (E + nb - 1) / nb;
    int s = 1; while (s * s < mean) s++;                  // ceil sqrt
    int cap = (mean + 8 * s + 15) & ~15;                  // 4608
    if (cap > CAPC) cap = CAPC;

    char* base = (char*)d_ws;
    size_t o = 0;
    auto alloc = [&](size_t bytes) { char* p = base + o; o = (o + bytes + 255) & ~(size_t)255; return p; };
    u16*  h1      = (u16*) alloc((size_t)N * 64 * 2);
    u16*  h2      = (u16*) alloc((size_t)N * 32 * 2);
    int2* es      = (int2*)alloc((size_t)nb * cap * 8);
    int2* es2     = (int2*)alloc((size_t)nb * cap * 8);
    int2* off2    = (int2*)alloc((size_t)N * 8);
    int*  gcursor = (int*) alloc(512 * 4);
    u16*  wfg     = (u16*) alloc(8192 * 2);               // W1 frags, 16 KB

    const int pblocks = (E + CHUNK - 1) / CHUNK;   // 782 partition blocks
    const int ntiles  = (N + 63) / 64;             // 1563 row tiles
    const int gblocks = ntiles < GBLK ? ntiles : GBLK;   // 1024 persistent

    init_kernel<<<8, 256, 0, stream>>>(W1, wfg, gcursor);
    g1p_kernel<<<pblocks + gblocks, 256, 0, stream>>>(
        x, wfg, h1, N, esrc, edst, ew, gcursor, es, E, cap, pblocks);
    sg1_kernel<<<2 * nb, 512, 0, stream>>>(h1, es, gcursor, es2, off2, b1, W2, h2, N, cap);
    gather2_kernel<<<(N + 63) / 64, 256, 0, stream>>>(h2, es2, off2, b2, out, N);
}